// Round 3
// baseline (724.853 us; speedup 1.0000x reference)
//
#include <hip/hip_runtime.h>
#include <hip/hip_bf16.h>

#define S_DIM 4096
#define E_DIM 2048

typedef __attribute__((ext_vector_type(4))) float f32x4;
typedef __attribute__((ext_vector_type(8))) short bf16x8;

__device__ __forceinline__ unsigned short f2bf(float f) {
  unsigned u = __builtin_bit_cast(unsigned, f);
  u += 0x7FFFu + ((u >> 16) & 1u);   // RNE
  return (unsigned short)(u >> 16);
}
__device__ __forceinline__ float bf2f(unsigned short h) {
  return __builtin_bit_cast(float, ((unsigned)h) << 16);
}

// ---------------- split f32 -> bf16 hi + bf16 lo ----------------
__global__ __launch_bounds__(256) void split_kernel(const float* __restrict__ in,
                                                    unsigned short* __restrict__ hi,
                                                    unsigned short* __restrict__ lo,
                                                    int n4) {
  int i = blockIdx.x * 256 + threadIdx.x;
  if (i >= n4) return;
  float4 v = reinterpret_cast<const float4*>(in)[i];
  float vv[4] = {v.x, v.y, v.z, v.w};
  unsigned short hh[4], ll[4];
#pragma unroll
  for (int r = 0; r < 4; ++r) {
    hh[r] = f2bf(vv[r]);
    ll[r] = f2bf(vv[r] - bf2f(hh[r]));
  }
  ushort4 h, l;
  h.x = hh[0]; h.y = hh[1]; h.z = hh[2]; h.w = hh[3];
  l.x = ll[0]; l.y = ll[1]; l.z = ll[2]; l.w = ll[3];
  reinterpret_cast<ushort4*>(hi)[i] = h;
  reinterpret_cast<ushort4*>(lo)[i] = l;
}

// ---------------- GEMM  C = A @ B^T  (A:[M,K] row-major, B:[N,K] row-major, bf16) ----------
// Tile 128x128, BK=32, 4 waves (2x2), each wave 64x64 = 4x4 frags of 16x16x32 MFMA.
// Staging via global_load_lds width 16 (m97 structure, 2 barriers per K-step).

__device__ __forceinline__ void stage_tile(char* lds_tile, const unsigned short* g,
                                           int row0, int k0, int ld, int tid) {
#pragma unroll
  for (int p = 0; p < 2; ++p) {
    const int off = tid * 16 + p * 4096;        // byte offset within 8192B tile
    const int row = off >> 6;                    // 64B per tile row (32 bf16)
    const int colb = off & 63;
    const char* ga = reinterpret_cast<const char*>(g + (size_t)(row0 + row) * ld + k0) + colb;
    char* la = lds_tile + (off & ~1023);         // wave-uniform base; HW adds lane*16
    __builtin_amdgcn_global_load_lds(
        (const __attribute__((address_space(1))) void*)ga,
        (__attribute__((address_space(3))) void*)la,
        16, 0, 0);
  }
}

enum { EPI_HILO = 0, EPI_TBF16 = 1, EPI_F32 = 2, EPI_BF16 = 3 };

template <bool SPLIT, int EPI>
__global__ __launch_bounds__(256, 2) void gemm_nt(
    const unsigned short* __restrict__ Ah, const unsigned short* __restrict__ Al,
    const unsigned short* __restrict__ Bh, const unsigned short* __restrict__ Bl,
    int lda, int ldb, int K,
    float* __restrict__ Cf, unsigned short* __restrict__ Ch, unsigned short* __restrict__ Cl,
    int ldc, float scale) {
  extern __shared__ char smem[];
  char* sA  = smem;             // 8192 B
  char* sB  = smem + 8192;      // 8192 B
  char* sAl = smem + 16384;     // 8192 B (SPLIT only)
  char* sBl = smem + 24576;     // 8192 B (SPLIT only)

  const int tid = threadIdx.x;
  const int row0A = blockIdx.y * 128;
  const int row0B = blockIdx.x * 128;

  const int wave = tid >> 6;
  const int lane = tid & 63;
  const int wr = (wave >> 1) * 64;
  const int wc = (wave & 1) * 64;
  const int l15 = lane & 15;
  const int kg = lane >> 4;

  f32x4 acc[4][4];
#pragma unroll
  for (int m = 0; m < 4; ++m)
#pragma unroll
    for (int n = 0; n < 4; ++n) acc[m][n] = (f32x4){0.f, 0.f, 0.f, 0.f};

  for (int kt = 0; kt < K; kt += 32) {
    __syncthreads();   // previous iteration's LDS reads done
    stage_tile(sA, Ah, row0A, kt, lda, tid);
    stage_tile(sB, Bh, row0B, kt, ldb, tid);
    if (SPLIT) {
      stage_tile(sAl, Al, row0A, kt, lda, tid);
      stage_tile(sBl, Bl, row0B, kt, ldb, tid);
    }
    __syncthreads();   // compiler drains vmcnt(0) before barrier -> tiles ready

    bf16x8 a_h[4], b_h[4], a_l[4], b_l[4];
#pragma unroll
    for (int m = 0; m < 4; ++m) {
      const int ra = (wr + m * 16 + l15) * 64 + kg * 16;   // byte offset
      const int rb = (wc + m * 16 + l15) * 64 + kg * 16;
      a_h[m] = *reinterpret_cast<const bf16x8*>(sA + ra);
      b_h[m] = *reinterpret_cast<const bf16x8*>(sB + rb);
      if (SPLIT) {
        a_l[m] = *reinterpret_cast<const bf16x8*>(sAl + ra);
        b_l[m] = *reinterpret_cast<const bf16x8*>(sBl + rb);
      }
    }
#pragma unroll
    for (int m = 0; m < 4; ++m)
#pragma unroll
      for (int n = 0; n < 4; ++n) {
        acc[m][n] = __builtin_amdgcn_mfma_f32_16x16x32_bf16(a_h[m], b_h[n], acc[m][n], 0, 0, 0);
        if (SPLIT) {
          acc[m][n] = __builtin_amdgcn_mfma_f32_16x16x32_bf16(a_h[m], b_l[n], acc[m][n], 0, 0, 0);
          acc[m][n] = __builtin_amdgcn_mfma_f32_16x16x32_bf16(a_l[m], b_h[n], acc[m][n], 0, 0, 0);
        }
      }
  }

  // epilogue: C/D frag mapping col=lane&15, row=(lane>>4)*4+reg  [m89/m91 verified]
#pragma unroll
  for (int m = 0; m < 4; ++m)
#pragma unroll
    for (int n = 0; n < 4; ++n) {
      const int row = row0A + wr + m * 16 + kg * 4;
      const int col = row0B + wc + n * 16 + l15;
      f32x4 v = acc[m][n];
      if constexpr (EPI == EPI_F32) {
#pragma unroll
        for (int r = 0; r < 4; ++r)
          Cf[(size_t)(row + r) * ldc + col] = v[r] * scale;
      } else if constexpr (EPI == EPI_BF16) {
#pragma unroll
        for (int r = 0; r < 4; ++r)
          Ch[(size_t)(row + r) * ldc + col] = f2bf(v[r] * scale);
      } else if constexpr (EPI == EPI_HILO) {
#pragma unroll
        for (int r = 0; r < 4; ++r) {
          float s = v[r] * scale;
          unsigned short h = f2bf(s);
          Ch[(size_t)(row + r) * ldc + col] = h;
          Cl[(size_t)(row + r) * ldc + col] = f2bf(s - bf2f(h));
        }
      } else {  // EPI_TBF16: write C^T (bf16), ldc = leading dim of transposed output
        unsigned short tmp[4];
#pragma unroll
        for (int r = 0; r < 4; ++r) tmp[r] = f2bf(v[r] * scale);
        ushort4 pk;
        pk.x = tmp[0]; pk.y = tmp[1]; pk.z = tmp[2]; pk.w = tmp[3];
        *reinterpret_cast<ushort4*>(Ch + (size_t)col * ldc + row) = pk;
      }
    }
}

// ---------------- row softmax: S (bf16 [4096][4096]) -> P (bf16) ----------------
__global__ __launch_bounds__(256) void softmax_kernel(const unsigned short* __restrict__ Sm,
                                                      unsigned short* __restrict__ P) {
  const int row = blockIdx.x;
  const int tid = threadIdx.x;
  const unsigned short* src = Sm + (size_t)row * S_DIM;
  float vals[16];
  float mx = -1e30f;
#pragma unroll
  for (int i = 0; i < 4; ++i) {
    ushort4 h = reinterpret_cast<const ushort4*>(src)[tid + i * 256];
    float a = bf2f(h.x), b = bf2f(h.y), c = bf2f(h.z), d = bf2f(h.w);
    vals[i * 4 + 0] = a; vals[i * 4 + 1] = b;
    vals[i * 4 + 2] = c; vals[i * 4 + 3] = d;
    mx = fmaxf(mx, fmaxf(fmaxf(a, b), fmaxf(c, d)));
  }
#pragma unroll
  for (int off = 32; off >= 1; off >>= 1) mx = fmaxf(mx, __shfl_xor(mx, off, 64));
  __shared__ float red[8];
  const int wave = tid >> 6, lane = tid & 63;
  if (lane == 0) red[wave] = mx;
  __syncthreads();
  mx = fmaxf(fmaxf(red[0], red[1]), fmaxf(red[2], red[3]));
  float sum = 0.f;
#pragma unroll
  for (int i = 0; i < 16; ++i) { vals[i] = __expf(vals[i] - mx); sum += vals[i]; }
#pragma unroll
  for (int off = 32; off >= 1; off >>= 1) sum += __shfl_xor(sum, off, 64);
  if (lane == 0) red[4 + wave] = sum;
  __syncthreads();
  sum = red[4] + red[5] + red[6] + red[7];
  const float inv = 1.0f / sum;
  unsigned short* dst = P + (size_t)row * S_DIM;
#pragma unroll
  for (int i = 0; i < 4; ++i) {
    ushort4 pk;
    pk.x = f2bf(vals[i * 4 + 0] * inv);
    pk.y = f2bf(vals[i * 4 + 1] * inv);
    pk.z = f2bf(vals[i * 4 + 2] * inv);
    pk.w = f2bf(vals[i * 4 + 3] * inv);
    reinterpret_cast<ushort4*>(dst)[tid + i * 256] = pk;
  }
}

extern "C" void kernel_launch(void* const* d_in, const int* in_sizes, int n_in,
                              void* d_out, int out_size, void* d_ws, size_t ws_size,
                              hipStream_t stream) {
  const float* x  = (const float*)d_in[0];
  const float* Wq = (const float*)d_in[1];
  const float* Wk = (const float*)d_in[2];
  const float* Wv = (const float*)d_in[3];
  float* out = (float*)d_out;
  char* ws = (char*)d_ws;

  const size_t SZ_XE = (size_t)S_DIM * E_DIM * 2;  // 16 MiB (bf16 S x E)
  const size_t SZ_EE = (size_t)E_DIM * E_DIM * 2;  // 8 MiB  (bf16 E x E)
  const size_t NEED = 8 * SZ_XE;                   // 128 MiB peak
  if (ws_size < NEED) return;  // visible absmax failure instead of OOB crash

  // Layout (128 MiB):
  //   [0,32M)    qh,ql          -> later aliased by P (bf16 4096x4096, 32M)
  //   [32M,64M)  kh,kl
  //   [64M,80M)  vt (V^T bf16 [2048][4096])
  //   [80M,112M) xh,xl          -> later aliased by S (bf16 4096x4096, 32M total)
  //   [112M,128M) w-slot hi/lo  (reused for Wq, Wk, Wv)
  unsigned short* qh = (unsigned short*)(ws);
  unsigned short* ql = (unsigned short*)(ws + 1 * SZ_XE);
  unsigned short* kh = (unsigned short*)(ws + 2 * SZ_XE);
  unsigned short* kl = (unsigned short*)(ws + 3 * SZ_XE);
  unsigned short* vt = (unsigned short*)(ws + 4 * SZ_XE);
  unsigned short* xh = (unsigned short*)(ws + 5 * SZ_XE);
  unsigned short* xl = (unsigned short*)(ws + 6 * SZ_XE);
  unsigned short* wh = (unsigned short*)(ws + 7 * SZ_XE);
  unsigned short* wl = (unsigned short*)(ws + 7 * SZ_XE + SZ_EE);
  // aliases (stream-ordered; producers of the aliased regions are dead)
  unsigned short* Sbf = xh;  // 32 MiB spans xh+xl regions (both dead after V projection)
  unsigned short* P   = qh;  // 32 MiB spans qh+ql regions (dead after QK^T)

  const int nx4 = S_DIM * E_DIM / 4;
  const int nw4 = E_DIM * E_DIM / 4;

  // 1) split x
  split_kernel<<<(nx4 + 255) / 256, 256, 0, stream>>>(x, xh, xl, nx4);

  dim3 gProj(E_DIM / 128, S_DIM / 128);
  // 2) Q projection (hi/lo out)
  split_kernel<<<(nw4 + 255) / 256, 256, 0, stream>>>(Wq, wh, wl, nw4);
  gemm_nt<true, EPI_HILO><<<gProj, 256, 32768, stream>>>(
      xh, xl, wh, wl, E_DIM, E_DIM, E_DIM, nullptr, qh, ql, E_DIM, 1.0f);
  // 3) K projection (hi/lo out)
  split_kernel<<<(nw4 + 255) / 256, 256, 0, stream>>>(Wk, wh, wl, nw4);
  gemm_nt<true, EPI_HILO><<<gProj, 256, 32768, stream>>>(
      xh, xl, wh, wl, E_DIM, E_DIM, E_DIM, nullptr, kh, kl, E_DIM, 1.0f);
  // 4) V projection (transposed bf16 out)
  split_kernel<<<(nw4 + 255) / 256, 256, 0, stream>>>(Wv, wh, wl, nw4);
  gemm_nt<true, EPI_TBF16><<<gProj, 256, 32768, stream>>>(
      xh, xl, wh, wl, E_DIM, E_DIM, E_DIM, nullptr, vt, nullptr, S_DIM, 1.0f);

  // 5) S = (Q @ K^T) / sqrt(E)  -> single bf16 (aliases dead x splits; 32 MiB fits exactly)
  dim3 gQK(S_DIM / 128, S_DIM / 128);
  const float scale = 0.022097086912079608f;  // 1/sqrt(2048)
  gemm_nt<true, EPI_BF16><<<gQK, 256, 32768, stream>>>(
      qh, ql, kh, kl, E_DIM, E_DIM, E_DIM, nullptr, Sbf, nullptr, S_DIM, scale);

  // 6) row softmax -> P bf16 (aliases dead q splits)
  softmax_kernel<<<S_DIM, 256, 0, stream>>>(Sbf, P);

  // 7) out = P @ V = P @ (V^T)^T, f32
  dim3 gPV(E_DIM / 128, S_DIM / 128);
  gemm_nt<false, EPI_F32><<<gPV, 256, 16384, stream>>>(
      P, nullptr, vt, nullptr, S_DIM, S_DIM, S_DIM, out, nullptr, nullptr, E_DIM, 1.0f);
}

// Round 4
// 445.613 us; speedup vs baseline: 1.6266x; 1.6266x over previous
//
#include <hip/hip_runtime.h>
#include <hip/hip_bf16.h>

#define S_DIM 4096
#define E_DIM 2048

typedef __attribute__((ext_vector_type(4))) float f32x4;
typedef __attribute__((ext_vector_type(8))) short bf16x8;

__device__ __forceinline__ unsigned short f2bf(float f) {
  unsigned u = __builtin_bit_cast(unsigned, f);
  u += 0x7FFFu + ((u >> 16) & 1u);   // RNE
  return (unsigned short)(u >> 16);
}
__device__ __forceinline__ float bf2f(unsigned short h) {
  return __builtin_bit_cast(float, ((unsigned)h) << 16);
}

// ---------------- cast f32 -> bf16 ----------------
__global__ __launch_bounds__(256) void cast_kernel(const float* __restrict__ in,
                                                   unsigned short* __restrict__ out,
                                                   int n4) {
  int i = blockIdx.x * 256 + threadIdx.x;
  if (i >= n4) return;
  float4 v = reinterpret_cast<const float4*>(in)[i];
  ushort4 o;
  o.x = f2bf(v.x); o.y = f2bf(v.y); o.z = f2bf(v.z); o.w = f2bf(v.w);
  reinterpret_cast<ushort4*>(out)[i] = o;
}

// ---------------- GEMM  C = A @ B^T  (A:[M,K] row-major, B:[N,K] row-major, bf16) ----------
// m97 structure: tile 128x128, BK=32, 4 waves (2x2), each wave 64x64 = 4x4 frags
// of 16x16x32 MFMA; staging via global_load_lds width 16; 2 barriers per K-step.

__device__ __forceinline__ void stage_tile(char* lds_tile, const unsigned short* g,
                                           int row0, int k0, int ld, int tid) {
#pragma unroll
  for (int p = 0; p < 2; ++p) {
    const int off = tid * 16 + p * 4096;        // byte offset within 8192B tile
    const int row = off >> 6;                    // 64B per tile row (32 bf16)
    const int colb = off & 63;
    const char* ga = reinterpret_cast<const char*>(g + (size_t)(row0 + row) * ld + k0) + colb;
    char* la = lds_tile + (off & ~1023);         // wave-uniform base; HW adds lane*16
    __builtin_amdgcn_global_load_lds(
        (const __attribute__((address_space(1))) void*)ga,
        (__attribute__((address_space(3))) void*)la,
        16, 0, 0);
  }
}

enum { EPI_TBF16 = 1, EPI_F32 = 2, EPI_BF16 = 3 };

template <int EPI>
__global__ __launch_bounds__(256, 2) void gemm_nt(
    const unsigned short* __restrict__ A, const unsigned short* __restrict__ B,
    int lda, int ldb, int K,
    float* __restrict__ Cf, unsigned short* __restrict__ Cb,
    int ldc, float scale) {
  extern __shared__ char smem[];
  char* sA = smem;              // 8192 B
  char* sB = smem + 8192;       // 8192 B

  const int tid = threadIdx.x;
  const int row0A = blockIdx.y * 128;
  const int row0B = blockIdx.x * 128;

  const int wave = tid >> 6;
  const int lane = tid & 63;
  const int wr = (wave >> 1) * 64;
  const int wc = (wave & 1) * 64;
  const int l15 = lane & 15;
  const int kg = lane >> 4;

  f32x4 acc[4][4];
#pragma unroll
  for (int m = 0; m < 4; ++m)
#pragma unroll
    for (int n = 0; n < 4; ++n) acc[m][n] = (f32x4){0.f, 0.f, 0.f, 0.f};

  for (int kt = 0; kt < K; kt += 32) {
    __syncthreads();   // previous iteration's LDS reads done
    stage_tile(sA, A, row0A, kt, lda, tid);
    stage_tile(sB, B, row0B, kt, ldb, tid);
    __syncthreads();   // compiler drains vmcnt(0) before barrier -> tiles ready

    bf16x8 a_f[4], b_f[4];
#pragma unroll
    for (int m = 0; m < 4; ++m) {
      const int ra = (wr + m * 16 + l15) * 64 + kg * 16;   // byte offset
      const int rb = (wc + m * 16 + l15) * 64 + kg * 16;
      a_f[m] = *reinterpret_cast<const bf16x8*>(sA + ra);
      b_f[m] = *reinterpret_cast<const bf16x8*>(sB + rb);
    }
#pragma unroll
    for (int m = 0; m < 4; ++m)
#pragma unroll
      for (int n = 0; n < 4; ++n)
        acc[m][n] = __builtin_amdgcn_mfma_f32_16x16x32_bf16(a_f[m], b_f[n], acc[m][n], 0, 0, 0);
  }

  // epilogue: C/D frag mapping col=lane&15, row=(lane>>4)*4+reg  [m89/m91 verified]
#pragma unroll
  for (int m = 0; m < 4; ++m)
#pragma unroll
    for (int n = 0; n < 4; ++n) {
      const int row = row0A + wr + m * 16 + kg * 4;
      const int col = row0B + wc + n * 16 + l15;
      f32x4 v = acc[m][n];
      if constexpr (EPI == EPI_F32) {
#pragma unroll
        for (int r = 0; r < 4; ++r)
          Cf[(size_t)(row + r) * ldc + col] = v[r] * scale;
      } else if constexpr (EPI == EPI_BF16) {
#pragma unroll
        for (int r = 0; r < 4; ++r)
          Cb[(size_t)(row + r) * ldc + col] = f2bf(v[r] * scale);
      } else {  // EPI_TBF16: write C^T (bf16), ldc = leading dim of transposed output
        unsigned short tmp[4];
#pragma unroll
        for (int r = 0; r < 4; ++r) tmp[r] = f2bf(v[r] * scale);
        ushort4 pk;
        pk.x = tmp[0]; pk.y = tmp[1]; pk.z = tmp[2]; pk.w = tmp[3];
        *reinterpret_cast<ushort4*>(Cb + (size_t)col * ldc + row) = pk;
      }
    }
}

// ---------------- row softmax: S (bf16 [4096][4096]) -> P (bf16) ----------------
__global__ __launch_bounds__(256) void softmax_kernel(const unsigned short* __restrict__ Sm,
                                                      unsigned short* __restrict__ P) {
  const int row = blockIdx.x;
  const int tid = threadIdx.x;
  const unsigned short* src = Sm + (size_t)row * S_DIM;
  float vals[16];
  float mx = -1e30f;
#pragma unroll
  for (int i = 0; i < 4; ++i) {
    ushort4 h = reinterpret_cast<const ushort4*>(src)[tid + i * 256];
    float a = bf2f(h.x), b = bf2f(h.y), c = bf2f(h.z), d = bf2f(h.w);
    vals[i * 4 + 0] = a; vals[i * 4 + 1] = b;
    vals[i * 4 + 2] = c; vals[i * 4 + 3] = d;
    mx = fmaxf(mx, fmaxf(fmaxf(a, b), fmaxf(c, d)));
  }
#pragma unroll
  for (int off = 32; off >= 1; off >>= 1) mx = fmaxf(mx, __shfl_xor(mx, off, 64));
  __shared__ float red[8];
  const int wave = tid >> 6, lane = tid & 63;
  if (lane == 0) red[wave] = mx;
  __syncthreads();
  mx = fmaxf(fmaxf(red[0], red[1]), fmaxf(red[2], red[3]));
  float sum = 0.f;
#pragma unroll
  for (int i = 0; i < 16; ++i) { vals[i] = __expf(vals[i] - mx); sum += vals[i]; }
#pragma unroll
  for (int off = 32; off >= 1; off >>= 1) sum += __shfl_xor(sum, off, 64);
  if (lane == 0) red[4 + wave] = sum;
  __syncthreads();
  sum = red[4] + red[5] + red[6] + red[7];
  const float inv = 1.0f / sum;
  unsigned short* dst = P + (size_t)row * S_DIM;
#pragma unroll
  for (int i = 0; i < 4; ++i) {
    ushort4 pk;
    pk.x = f2bf(vals[i * 4 + 0] * inv);
    pk.y = f2bf(vals[i * 4 + 1] * inv);
    pk.z = f2bf(vals[i * 4 + 2] * inv);
    pk.w = f2bf(vals[i * 4 + 3] * inv);
    reinterpret_cast<ushort4*>(dst)[tid + i * 256] = pk;
  }
}

extern "C" void kernel_launch(void* const* d_in, const int* in_sizes, int n_in,
                              void* d_out, int out_size, void* d_ws, size_t ws_size,
                              hipStream_t stream) {
  const float* x  = (const float*)d_in[0];
  const float* Wq = (const float*)d_in[1];
  const float* Wk = (const float*)d_in[2];
  const float* Wv = (const float*)d_in[3];
  float* out = (float*)d_out;
  char* ws = (char*)d_ws;

  const size_t MB = 1024 * 1024;
  const size_t NEED = 104 * MB;
  if (ws_size < NEED) return;  // visible absmax failure instead of OOB crash

  // Layout (104 MiB):
  //   [0,16M)    q bf16 [4096][2048]   }-- later aliased by P (bf16 4096x4096, 32M)
  //   [16,32M)   k bf16 [4096][2048]   }
  //   [32,48M)   vt bf16 [2048][4096]
  //   [48,64M)   xb bf16 [4096][2048]
  //   [64,72M)   wb bf16 [2048][2048]  (reused for Wq, Wk, Wv)
  //   [72,104M)  S  bf16 [4096][4096]
  unsigned short* qb = (unsigned short*)(ws);
  unsigned short* kb = (unsigned short*)(ws + 16 * MB);
  unsigned short* vt = (unsigned short*)(ws + 32 * MB);
  unsigned short* xb = (unsigned short*)(ws + 48 * MB);
  unsigned short* wb = (unsigned short*)(ws + 64 * MB);
  unsigned short* Sb = (unsigned short*)(ws + 72 * MB);
  unsigned short* P  = qb;  // 32 MiB spans q+k regions (both dead after QK^T)

  const int nx4 = S_DIM * E_DIM / 4;
  const int nw4 = E_DIM * E_DIM / 4;

  // 1) casts + projections (1-pass bf16)
  cast_kernel<<<(nx4 + 255) / 256, 256, 0, stream>>>(x, xb, nx4);

  dim3 gProj(E_DIM / 128, S_DIM / 128);
  cast_kernel<<<(nw4 + 255) / 256, 256, 0, stream>>>(Wq, wb, nw4);
  gemm_nt<EPI_BF16><<<gProj, 256, 16384, stream>>>(
      xb, wb, E_DIM, E_DIM, E_DIM, nullptr, qb, E_DIM, 1.0f);
  cast_kernel<<<(nw4 + 255) / 256, 256, 0, stream>>>(Wk, wb, nw4);
  gemm_nt<EPI_BF16><<<gProj, 256, 16384, stream>>>(
      xb, wb, E_DIM, E_DIM, E_DIM, nullptr, kb, E_DIM, 1.0f);
  cast_kernel<<<(nw4 + 255) / 256, 256, 0, stream>>>(Wv, wb, nw4);
  gemm_nt<EPI_TBF16><<<gProj, 256, 16384, stream>>>(
      xb, wb, E_DIM, E_DIM, E_DIM, nullptr, vt, S_DIM, 1.0f);

  // 2) S = (Q @ K^T) / sqrt(E) -> bf16
  dim3 gQK(S_DIM / 128, S_DIM / 128);
  const float scale = 0.022097086912079608f;  // 1/sqrt(2048)
  gemm_nt<EPI_BF16><<<gQK, 256, 16384, stream>>>(
      qb, kb, E_DIM, E_DIM, E_DIM, nullptr, Sb, S_DIM, scale);

  // 3) row softmax -> P bf16 (aliases dead q+k)
  softmax_kernel<<<S_DIM, 256, 0, stream>>>(Sb, P);

  // 4) out = P @ V = P @ (V^T)^T, f32
  dim3 gPV(E_DIM / 128, S_DIM / 128);
  gemm_nt<EPI_F32><<<gPV, 256, 16384, stream>>>(
      P, vt, S_DIM, S_DIM, S_DIM, out, nullptr, E_DIM, 1.0f);
}

// Round 6
// 418.446 us; speedup vs baseline: 1.7322x; 1.0649x over previous
//
#include <hip/hip_runtime.h>
#include <hip/hip_bf16.h>

#define S_DIM 4096
#define E_DIM 2048

typedef __attribute__((ext_vector_type(4))) float f32x4;
typedef __attribute__((ext_vector_type(8))) short bf16x8;

__device__ __forceinline__ unsigned short f2bf(float f) {
  unsigned u = __builtin_bit_cast(unsigned, f);
  u += 0x7FFFu + ((u >> 16) & 1u);   // RNE
  return (unsigned short)(u >> 16);
}
__device__ __forceinline__ float bf2f(unsigned short h) {
  return __builtin_bit_cast(float, ((unsigned)h) << 16);
}

// ---------------- cast f32 -> bf16 ----------------
__global__ __launch_bounds__(256) void cast_kernel(const float* __restrict__ in,
                                                   unsigned short* __restrict__ out,
                                                   int n4) {
  int i = blockIdx.x * 256 + threadIdx.x;
  if (i >= n4) return;
  float4 v = reinterpret_cast<const float4*>(in)[i];
  ushort4 o;
  o.x = f2bf(v.x); o.y = f2bf(v.y); o.z = f2bf(v.z); o.w = f2bf(v.w);
  reinterpret_cast<ushort4*>(out)[i] = o;
}

// ---------------- add f32 partials ----------------
__global__ __launch_bounds__(256) void add_kernel(const float* __restrict__ a,
                                                  const float* __restrict__ b,
                                                  float* __restrict__ o, int n4) {
  int i = blockIdx.x * 256 + threadIdx.x;
  if (i >= n4) return;
  float4 va = reinterpret_cast<const float4*>(a)[i];
  float4 vb = reinterpret_cast<const float4*>(b)[i];
  float4 vo = {va.x + vb.x, va.y + vb.y, va.z + vb.z, va.w + vb.w};
  reinterpret_cast<float4*>(o)[i] = vo;
}

// ======================= 8-phase 256x256 NT GEMM (bf16) =======================
// C = A @ B^T.  BM=BN=256, BK=64, 512 threads = 8 waves (2M x 4N).
// LDS 128 KiB: 2 buffers x (A 32K + B 32K); each A/B tile = 2 halves of
// 128x64 bf16; each half = 16 subtiles of [16 rows][32 bf16] (1024 B),
// st_16x32 swizzle: byte ^= ((byte>>9)&1)<<5 within each subtile.
// Staging: global_load_lds w16, LINEAR LDS dest, inverse-swizzled global src;
// ds_read applies the same swizzle (both-sides-or-neither, m201/m231).
// Per K-tile: 4 phases {ds_read | stage | bar | lgkm0+schedbar | setprio+16 MFMA | bar};
// s3(t+1) staged at P1, s0..s2(t+2) at P4; vmcnt(6) only at P4 (never 0 mid-loop).

__device__ __forceinline__ void stage_half(const unsigned short* __restrict__ g,
                                           int grow0, int ld, int kByte0,
                                           char* ldsHalfBase, int tid) {
#pragma unroll
  for (int p = 0; p < 2; ++p) {
    const int o = (p * 512 + tid) * 16;            // linear LDS byte offset
    const int S = o >> 10;                         // subtile 0..15
    const int oi = o & 1023;
    const int osi = oi ^ (((oi >> 9) & 1) << 5);   // inverse swizzle on source
    const int r  = (S >> 1) * 16 + (osi >> 6);     // row in half-tile 0..127
    const int cb = (S & 1) * 64 + (osi & 63);      // byte col 0..127
    const char* ga = reinterpret_cast<const char*>(g) +
                     ((size_t)(grow0 + r) * ld) * 2 + kByte0 + cb;
    char* la = ldsHalfBase + (o & ~1023);          // wave-uniform base; HW adds lane*16
    __builtin_amdgcn_global_load_lds(
        (const __attribute__((address_space(1))) void*)ga,
        (__attribute__((address_space(3))) void*)la, 16, 0, 0);
  }
}

#define MFMA_QUAD(AM, AN, AF, BF)                                              \
  _Pragma("unroll") for (int mm = 0; mm < 4; ++mm)                             \
  _Pragma("unroll") for (int nn = 0; nn < 2; ++nn)                             \
  _Pragma("unroll") for (int ks = 0; ks < 2; ++ks)                             \
    acc[(AM) + mm][(AN) + nn] = __builtin_amdgcn_mfma_f32_16x16x32_bf16(       \
        AF[mm][ks], BF[nn][ks], acc[(AM) + mm][(AN) + nn], 0, 0, 0);

enum { EPI_QKV = 0, EPI_BF16 = 1, EPI_F32 = 2 };

template <int EPI>
__global__ __launch_bounds__(512, 2) void gemm8(
    const unsigned short* __restrict__ A, const unsigned short* __restrict__ B,
    int lda, int ldb, int K,
    float* __restrict__ Cf, unsigned short* __restrict__ Cb,
    unsigned short* __restrict__ Ct, int ldc, float scale,
    int kElemPerZ, long long zStrideC) {
  extern __shared__ char lds[];

  const int tid = threadIdx.x;
  const int rowA0 = blockIdx.y * 256;
  const int rowB0 = blockIdx.x * 256;
  const int k0B = blockIdx.z * kElemPerZ * 2;   // k byte offset for this z-slice
  if (EPI == EPI_F32) Cf += (size_t)blockIdx.z * zStrideC;

  const int wave = tid >> 6;
  const int lane = tid & 63;
  const int wm = wave >> 2;   // 0..1 (M)
  const int wn = wave & 3;    // 0..3 (N)
  const int l15 = lane & 15;
  const int kg = lane >> 4;
  const int rsw = (l15 * 64 + kg * 16) ^ ((l15 & 8) << 2);  // swizzled in-subtile off

  int bSub[2][2];
#pragma unroll
  for (int nh = 0; nh < 2; ++nh)
#pragma unroll
    for (int nn = 0; nn < 2; ++nn) {
      const int row = wn * 64 + nh * 32 + nn * 16;
      bSub[nh][nn] = 32768 + (row >> 7) * 16384 + ((row & 127) >> 4) * 2048;
    }
  const int aBase = wm * 16384;

  f32x4 acc[8][4];
#pragma unroll
  for (int mi = 0; mi < 8; ++mi)
#pragma unroll
    for (int ni = 0; ni < 4; ++ni) acc[mi][ni] = (f32x4){0.f, 0.f, 0.f, 0.f};

  const int NT = K / 64;
  char* buf0 = lds;
  char* buf1 = lds + 65536;

  // ---- prologue: tile0 fully (8 loads/wave), tile1 s0..s2 (6); retire tile0
  stage_half(A, rowA0,       lda, k0B,       buf0 + 0,     tid);
  stage_half(A, rowA0 + 128, lda, k0B,       buf0 + 16384, tid);
  stage_half(B, rowB0,       ldb, k0B,       buf0 + 32768, tid);
  stage_half(B, rowB0 + 128, ldb, k0B,       buf0 + 49152, tid);
  stage_half(A, rowA0,       lda, k0B + 128, buf1 + 0,     tid);
  stage_half(A, rowA0 + 128, lda, k0B + 128, buf1 + 16384, tid);
  stage_half(B, rowB0,       ldb, k0B + 128, buf1 + 32768, tid);
  asm volatile("s_waitcnt vmcnt(6)" ::: "memory");
  __builtin_amdgcn_sched_barrier(0);
  __builtin_amdgcn_s_barrier();

  for (int t = 0; t < NT; ++t) {
    char* bufc = lds + (t & 1) * 65536;
    char* bufn = lds + ((t & 1) ^ 1) * 65536;
    bf16x8 a0[4][2], a1[4][2], b0[2][2], b1[2][2];

    // ---------- P1: read A-m0 (8) + B-n0 (4); stage s3(t+1); mfma (m0,n0)
#pragma unroll
    for (int mm = 0; mm < 4; ++mm)
#pragma unroll
      for (int ks = 0; ks < 2; ++ks)
        a0[mm][ks] = *reinterpret_cast<const bf16x8*>(
            bufc + aBase + (mm * 2 + ks) * 1024 + rsw);
#pragma unroll
    for (int nn = 0; nn < 2; ++nn)
#pragma unroll
      for (int ks = 0; ks < 2; ++ks)
        b0[nn][ks] = *reinterpret_cast<const bf16x8*>(
            bufc + bSub[0][nn] + ks * 1024 + rsw);
    if (t + 1 < NT)
      stage_half(B, rowB0 + 128, ldb, k0B + (t + 1) * 128, bufn + 49152, tid);
    asm volatile("s_waitcnt lgkmcnt(8)" ::: "memory");
    __builtin_amdgcn_s_barrier();
    asm volatile("s_waitcnt lgkmcnt(0)" ::: "memory");
    __builtin_amdgcn_sched_barrier(0);
    __builtin_amdgcn_s_setprio(1);
    MFMA_QUAD(0, 0, a0, b0)
    __builtin_amdgcn_s_setprio(0);
    __builtin_amdgcn_s_barrier();

    // ---------- P2: read B-n1 (4); mfma (m0,n1)
#pragma unroll
    for (int nn = 0; nn < 2; ++nn)
#pragma unroll
      for (int ks = 0; ks < 2; ++ks)
        b1[nn][ks] = *reinterpret_cast<const bf16x8*>(
            bufc + bSub[1][nn] + ks * 1024 + rsw);
    __builtin_amdgcn_s_barrier();
    asm volatile("s_waitcnt lgkmcnt(0)" ::: "memory");
    __builtin_amdgcn_sched_barrier(0);
    __builtin_amdgcn_s_setprio(1);
    MFMA_QUAD(0, 2, a0, b1)
    __builtin_amdgcn_s_setprio(0);
    __builtin_amdgcn_s_barrier();

    // ---------- P3: read A-m1 (8); mfma (m1,n1)
#pragma unroll
    for (int mm = 0; mm < 4; ++mm)
#pragma unroll
      for (int ks = 0; ks < 2; ++ks)
        a1[mm][ks] = *reinterpret_cast<const bf16x8*>(
            bufc + aBase + ((4 + mm) * 2 + ks) * 1024 + rsw);
    __builtin_amdgcn_s_barrier();
    asm volatile("s_waitcnt lgkmcnt(0)" ::: "memory");
    __builtin_amdgcn_sched_barrier(0);
    __builtin_amdgcn_s_setprio(1);
    MFMA_QUAD(4, 2, a1, b1)
    __builtin_amdgcn_s_setprio(0);
    __builtin_amdgcn_s_barrier();

    // ---------- P4: stage s0..s2(t+2) into bufc (its reads retired at P3);
    //             vmcnt(6) retires tile t+1's 8 loads; mfma (m1,n0)
    if (t + 2 < NT) {
      const int kb = k0B + (t + 2) * 128;
      stage_half(A, rowA0,       lda, kb, bufc + 0,     tid);
      stage_half(A, rowA0 + 128, lda, kb, bufc + 16384, tid);
      stage_half(B, rowB0,       ldb, kb, bufc + 32768, tid);
      asm volatile("s_waitcnt vmcnt(6)" ::: "memory");
    } else {
      asm volatile("s_waitcnt vmcnt(0)" ::: "memory");
    }
    __builtin_amdgcn_sched_barrier(0);
    __builtin_amdgcn_s_barrier();
    __builtin_amdgcn_s_setprio(1);
    MFMA_QUAD(4, 0, a1, b0)
    __builtin_amdgcn_s_setprio(0);
    __builtin_amdgcn_s_barrier();
  }

  // ---------- epilogue: C/D frag mapping col=lane&15, row=(lane>>4)*4+reg
  const int r0 = rowA0 + wm * 128;
  const int c0 = rowB0 + wn * 64;
#pragma unroll
  for (int mi = 0; mi < 8; ++mi) {
    const int row = r0 + (mi >> 2) * 64 + (mi & 3) * 16 + kg * 4;
#pragma unroll
    for (int ni = 0; ni < 4; ++ni) {
      const int col = c0 + (ni >> 1) * 32 + (ni & 1) * 16 + l15;
      f32x4 v = acc[mi][ni];
      if constexpr (EPI == EPI_F32) {
#pragma unroll
        for (int r = 0; r < 4; ++r)
          Cf[(size_t)(row + r) * ldc + col] = v[r];
      } else if constexpr (EPI == EPI_BF16) {
#pragma unroll
        for (int r = 0; r < 4; ++r)
          Cb[(size_t)(row + r) * ldc + col] = f2bf(v[r] * scale);
      } else {  // EPI_QKV: cols<4096 -> qkb [4096][4096]; cols>=4096 -> vt transposed
        if (rowB0 < 4096) {
#pragma unroll
          for (int r = 0; r < 4; ++r)
            Cb[(size_t)(row + r) * 4096 + col] = f2bf(v[r]);
        } else {
          ushort4 pk;
          pk.x = f2bf(v[0]); pk.y = f2bf(v[1]);
          pk.z = f2bf(v[2]); pk.w = f2bf(v[3]);
          *reinterpret_cast<ushort4*>(Ct + (size_t)(col - 4096) * 4096 + row) = pk;
        }
      }
    }
  }
}

// ---------------- row softmax: S (bf16 [4096][4096]) -> P (bf16) ----------------
__global__ __launch_bounds__(256) void softmax_kernel(const unsigned short* __restrict__ Sm,
                                                      unsigned short* __restrict__ P) {
  const int row = blockIdx.x;
  const int tid = threadIdx.x;
  const unsigned short* src = Sm + (size_t)row * S_DIM;
  float vals[16];
  float mx = -1e30f;
#pragma unroll
  for (int i = 0; i < 4; ++i) {
    ushort4 h = reinterpret_cast<const ushort4*>(src)[tid + i * 256];
    float a = bf2f(h.x), b = bf2f(h.y), c = bf2f(h.z), d = bf2f(h.w);
    vals[i * 4 + 0] = a; vals[i * 4 + 1] = b;
    vals[i * 4 + 2] = c; vals[i * 4 + 3] = d;
    mx = fmaxf(mx, fmaxf(fmaxf(a, b), fmaxf(c, d)));
  }
#pragma unroll
  for (int off = 32; off >= 1; off >>= 1) mx = fmaxf(mx, __shfl_xor(mx, off, 64));
  __shared__ float red[8];
  const int wave = tid >> 6, lane = tid & 63;
  if (lane == 0) red[wave] = mx;
  __syncthreads();
  mx = fmaxf(fmaxf(red[0], red[1]), fmaxf(red[2], red[3]));
  float sum = 0.f;
#pragma unroll
  for (int i = 0; i < 16; ++i) { vals[i] = __expf(vals[i] - mx); sum += vals[i]; }
#pragma unroll
  for (int off = 32; off >= 1; off >>= 1) sum += __shfl_xor(sum, off, 64);
  if (lane == 0) red[4 + wave] = sum;
  __syncthreads();
  sum = red[4] + red[5] + red[6] + red[7];
  const float inv = 1.0f / sum;
  unsigned short* dst = P + (size_t)row * S_DIM;
#pragma unroll
  for (int i = 0; i < 4; ++i) {
    ushort4 pk;
    pk.x = f2bf(vals[i * 4 + 0] * inv);
    pk.y = f2bf(vals[i * 4 + 1] * inv);
    pk.z = f2bf(vals[i * 4 + 2] * inv);
    pk.w = f2bf(vals[i * 4 + 3] * inv);
    reinterpret_cast<ushort4*>(dst)[tid + i * 256] = pk;
  }
}

extern "C" void kernel_launch(void* const* d_in, const int* in_sizes, int n_in,
                              void* d_out, int out_size, void* d_ws, size_t ws_size,
                              hipStream_t stream) {
  const float* x  = (const float*)d_in[0];
  const float* Wq = (const float*)d_in[1];
  const float* Wk = (const float*)d_in[2];
  const float* Wv = (const float*)d_in[3];
  float* out = (float*)d_out;
  char* ws = (char*)d_ws;

  const size_t MB = 1024 * 1024;
  const size_t NEED = 120 * MB;
  if (ws_size < NEED) return;  // visible absmax failure instead of OOB crash

  // Layout (120 MiB):
  //   [0,16)   xb bf16 [4096][2048]     }-> outp0 f32 [4096][2048] at PV (32M, over
  //   [16,40)  wcat bf16 [6144][2048]   }   dead xb + wcat head; wcat dead after proj)
  //   [40,72)  qkb bf16 [4096][4096] (Q cols 0-2047, K cols 2048-4095) -> P after QK
  //   [72,88)  vt bf16 [2048][4096]
  //   [88,120) Sb bf16 [4096][4096]     -> outp1 f32 at PV (over dead Sb)
  unsigned short* xb   = (unsigned short*)(ws);
  unsigned short* wcat = (unsigned short*)(ws + 16 * MB);
  unsigned short* qkb  = (unsigned short*)(ws + 40 * MB);
  unsigned short* vt   = (unsigned short*)(ws + 72 * MB);
  unsigned short* Sb   = (unsigned short*)(ws + 88 * MB);
  float* outp0 = (float*)(ws);
  float* outp1 = (float*)(ws + 88 * MB);
  unsigned short* P = qkb;

  // allow 128 KiB dynamic LDS (host-side attribute; graph-capture-safe)
  hipFuncSetAttribute(reinterpret_cast<const void*>(&gemm8<EPI_QKV>),
                      hipFuncAttributeMaxDynamicSharedMemorySize, 131072);
  hipFuncSetAttribute(reinterpret_cast<const void*>(&gemm8<EPI_BF16>),
                      hipFuncAttributeMaxDynamicSharedMemorySize, 131072);
  hipFuncSetAttribute(reinterpret_cast<const void*>(&gemm8<EPI_F32>),
                      hipFuncAttributeMaxDynamicSharedMemorySize, 131072);

  const int nx4 = S_DIM * E_DIM / 4;
  const int nw4 = E_DIM * E_DIM / 4;

  // 1) casts: x -> xb; Wq/Wk/Wv -> wcat rows 0/2048/4096
  cast_kernel<<<nx4 / 256, 256, 0, stream>>>(x, xb, nx4);
  cast_kernel<<<nw4 / 256, 256, 0, stream>>>(Wq, wcat, nw4);
  cast_kernel<<<nw4 / 256, 256, 0, stream>>>(Wk, wcat + (size_t)2048 * 2048, nw4);
  cast_kernel<<<nw4 / 256, 256, 0, stream>>>(Wv, wcat + (size_t)4096 * 2048, nw4);

  // 2) fused QKV projection: [4096][6144] = xb @ wcat^T; V-range written transposed
  gemm8<EPI_QKV><<<dim3(24, 16, 1), 512, 131072, stream>>>(
      xb, wcat, E_DIM, E_DIM, E_DIM, nullptr, qkb, vt, 4096, 1.0f, 0, 0);

  // 3) S = (Q @ K^T) * 1/sqrt(E) -> bf16
  const float scale = 0.022097086912079608f;
  gemm8<EPI_BF16><<<dim3(16, 16, 1), 512, 131072, stream>>>(
      qkb, qkb + 2048, 4096, 4096, E_DIM, nullptr, Sb, nullptr, 4096, scale, 0, 0);

  // 4) softmax -> P (aliases dead qkb)
  softmax_kernel<<<S_DIM, 256, 0, stream>>>(Sb, P);

  // 5) PV split-K=2: out_z = P[:, z*2048:+2048] @ vt[:, z*2048:+2048]^T
  //    z=0 -> outp0 = ws[0,32M); z=1 -> outp0 + 88MB/4 floats = outp1 (over dead Sb)
  gemm8<EPI_F32><<<dim3(8, 16, 2), 512, 131072, stream>>>(
      P, vt, 4096, 4096, 2048, outp0, nullptr, nullptr, E_DIM, 1.0f,
      2048, (long long)(88 * MB) / 4);

  // 6) out = outp0 + outp1
  add_kernel<<<nx4 / 256, 256, 0, stream>>>(outp0, outp1, out, nx4);
}

// Round 7
// 404.393 us; speedup vs baseline: 1.7924x; 1.0348x over previous
//
#include <hip/hip_runtime.h>
#include <hip/hip_bf16.h>

#define S_DIM 4096
#define E_DIM 2048

typedef __attribute__((ext_vector_type(4))) float f32x4;
typedef __attribute__((ext_vector_type(8))) short bf16x8;

__device__ __forceinline__ unsigned short f2bf(float f) {
  unsigned u = __builtin_bit_cast(unsigned, f);
  u += 0x7FFFu + ((u >> 16) & 1u);   // RNE
  return (unsigned short)(u >> 16);
}
__device__ __forceinline__ float bf2f(unsigned short h) {
  return __builtin_bit_cast(float, ((unsigned)h) << 16);
}

// ---------------- cast f32 -> bf16 ----------------
__global__ __launch_bounds__(256) void cast_kernel(const float* __restrict__ in,
                                                   unsigned short* __restrict__ out,
                                                   int n4) {
  int i = blockIdx.x * 256 + threadIdx.x;
  if (i >= n4) return;
  float4 v = reinterpret_cast<const float4*>(in)[i];
  ushort4 o;
  o.x = f2bf(v.x); o.y = f2bf(v.y); o.z = f2bf(v.z); o.w = f2bf(v.w);
  reinterpret_cast<ushort4*>(out)[i] = o;
}

// cast 3 weight matrices into concatenated wcat in one dispatch
__global__ __launch_bounds__(256) void cast3_kernel(const float* __restrict__ w0,
                                                    const float* __restrict__ w1,
                                                    const float* __restrict__ w2,
                                                    unsigned short* __restrict__ out,
                                                    int n4each) {
  int i = blockIdx.x * 256 + threadIdx.x;
  if (i >= 3 * n4each) return;
  const float* src = (i < n4each) ? w0 : (i < 2 * n4each ? w1 : w2);
  int j = (i < n4each) ? i : (i < 2 * n4each ? i - n4each : i - 2 * n4each);
  float4 v = reinterpret_cast<const float4*>(src)[j];
  ushort4 o;
  o.x = f2bf(v.x); o.y = f2bf(v.y); o.z = f2bf(v.z); o.w = f2bf(v.w);
  reinterpret_cast<ushort4*>(out)[i] = o;
}

// ---------------- add f32 partials ----------------
__global__ __launch_bounds__(256) void add_kernel(const float* __restrict__ a,
                                                  const float* __restrict__ b,
                                                  float* __restrict__ o, int n4) {
  int i = blockIdx.x * 256 + threadIdx.x;
  if (i >= n4) return;
  float4 va = reinterpret_cast<const float4*>(a)[i];
  float4 vb = reinterpret_cast<const float4*>(b)[i];
  float4 vo = {va.x + vb.x, va.y + vb.y, va.z + vb.z, va.w + vb.w};
  reinterpret_cast<float4*>(o)[i] = vo;
}

// ======================= 8-phase 256x256 NT GEMM (bf16) =======================
// C = A @ B^T.  BM=BN=256, BK=64, 512 threads = 8 waves (2M x 4N).
// LDS 128 KiB: 2 buffers x (A 32K + B 32K); halves of 128x64 bf16 stored as
// 16 subtiles of [16][32] bf16 (1024 B), st_16x32 swizzle (byte ^= ((b>>9)&1)<<5).
// Staging: global_load_lds w16, linear LDS dest + inverse-swizzled global src.
// Liveness-driven staging: bufc B-halves dead after P2 -> stage B(t+2) at P3;
// A-halves dead after P3 -> stage A(t+2) at P4; vmcnt(8) only at P4 (4 halves
// = 8 loads stay in flight; drained loads are >=4 phases old).

__device__ __forceinline__ void stage_half(const unsigned short* __restrict__ g,
                                           int grow0, int ld, int kByte0,
                                           char* ldsHalfBase, int tid) {
#pragma unroll
  for (int p = 0; p < 2; ++p) {
    const int o = (p * 512 + tid) * 16;            // linear LDS byte offset
    const int S = o >> 10;                         // subtile 0..15
    const int oi = o & 1023;
    const int osi = oi ^ (((oi >> 9) & 1) << 5);   // inverse swizzle on source
    const int r  = (S >> 1) * 16 + (osi >> 6);     // row in half-tile 0..127
    const int cb = (S & 1) * 64 + (osi & 63);      // byte col 0..127
    const char* ga = reinterpret_cast<const char*>(g) +
                     ((size_t)(grow0 + r) * ld) * 2 + kByte0 + cb;
    char* la = ldsHalfBase + (o & ~1023);          // wave-uniform base; HW adds lane*16
    __builtin_amdgcn_global_load_lds(
        (const __attribute__((address_space(1))) void*)ga,
        (__attribute__((address_space(3))) void*)la, 16, 0, 0);
  }
}

#define MFMA_QUAD(AM, AN, AF, BF)                                              \
  _Pragma("unroll") for (int mm = 0; mm < 4; ++mm)                             \
  _Pragma("unroll") for (int nn = 0; nn < 2; ++nn)                             \
  _Pragma("unroll") for (int ks = 0; ks < 2; ++ks)                             \
    acc[(AM) + mm][(AN) + nn] = __builtin_amdgcn_mfma_f32_16x16x32_bf16(       \
        AF[mm][ks], BF[nn][ks], acc[(AM) + mm][(AN) + nn], 0, 0, 0);

enum { EPI_QKV = 0, EPI_BF16 = 1, EPI_F32 = 2 };

template <int EPI>
__global__ __launch_bounds__(512, 2) void gemm8(
    const unsigned short* __restrict__ A, const unsigned short* __restrict__ B,
    int lda, int ldb, int K,
    float* __restrict__ Cf, unsigned short* __restrict__ Cb,
    unsigned short* __restrict__ Ct, int ldc, float scale,
    int kElemPerZ, long long zStrideC) {
  extern __shared__ char lds[];

  const int tid = threadIdx.x;
  // T1: bijective XCD swizzle (nwg % 8 == 0 for all our grids)
  int bx = blockIdx.x, by = blockIdx.y;
  {
    const int gx = gridDim.x;
    const int nwg = gx * gridDim.y;
    const int orig = by * gx + bx;
    const int q = nwg >> 3;
    const int s = (orig & 7) * q + (orig >> 3);
    bx = s % gx; by = s / gx;
  }
  const int rowA0 = by * 256;
  const int rowB0 = bx * 256;
  const int k0B = blockIdx.z * kElemPerZ * 2;   // k byte offset for this z-slice
  if (EPI == EPI_F32) Cf += (size_t)blockIdx.z * zStrideC;

  const int wave = tid >> 6;
  const int lane = tid & 63;
  const int wm = wave >> 2;   // 0..1 (M)
  const int wn = wave & 3;    // 0..3 (N)
  const int l15 = lane & 15;
  const int kg = lane >> 4;
  const int rsw = (l15 * 64 + kg * 16) ^ ((l15 & 8) << 2);  // swizzled in-subtile off

  int bSub[2][2];
#pragma unroll
  for (int nh = 0; nh < 2; ++nh)
#pragma unroll
    for (int nn = 0; nn < 2; ++nn) {
      const int row = wn * 64 + nh * 32 + nn * 16;
      bSub[nh][nn] = 32768 + (row >> 7) * 16384 + ((row & 127) >> 4) * 2048;
    }
  const int aBase = wm * 16384;

  f32x4 acc[8][4];
#pragma unroll
  for (int mi = 0; mi < 8; ++mi)
#pragma unroll
    for (int ni = 0; ni < 4; ++ni) acc[mi][ni] = (f32x4){0.f, 0.f, 0.f, 0.f};

  const int NT = K / 64;
  char* buf0 = lds;
  char* buf1 = lds + 65536;

  // ---- prologue: stage tile0 and tile1 fully (16 loads/thread); retire tile0
  stage_half(A, rowA0,       lda, k0B,       buf0 + 0,     tid);
  stage_half(A, rowA0 + 128, lda, k0B,       buf0 + 16384, tid);
  stage_half(B, rowB0,       ldb, k0B,       buf0 + 32768, tid);
  stage_half(B, rowB0 + 128, ldb, k0B,       buf0 + 49152, tid);
  stage_half(B, rowB0,       ldb, k0B + 128, buf1 + 32768, tid);
  stage_half(B, rowB0 + 128, ldb, k0B + 128, buf1 + 49152, tid);
  stage_half(A, rowA0,       lda, k0B + 128, buf1 + 0,     tid);
  stage_half(A, rowA0 + 128, lda, k0B + 128, buf1 + 16384, tid);
  asm volatile("s_waitcnt vmcnt(8)" ::: "memory");
  __builtin_amdgcn_sched_barrier(0);
  __builtin_amdgcn_s_barrier();

  for (int t = 0; t < NT; ++t) {
    char* bufc = lds + (t & 1) * 65536;
    bf16x8 a0[4][2], a1[4][2], b0[2][2], b1[2][2];

    // ---------- P1: read A-m0 (8) + B-n0 (4); mfma (m0,n0)
#pragma unroll
    for (int mm = 0; mm < 4; ++mm)
#pragma unroll
      for (int ks = 0; ks < 2; ++ks)
        a0[mm][ks] = *reinterpret_cast<const bf16x8*>(
            bufc + aBase + (mm * 2 + ks) * 1024 + rsw);
#pragma unroll
    for (int nn = 0; nn < 2; ++nn)
#pragma unroll
      for (int ks = 0; ks < 2; ++ks)
        b0[nn][ks] = *reinterpret_cast<const bf16x8*>(
            bufc + bSub[0][nn] + ks * 1024 + rsw);
    asm volatile("s_waitcnt lgkmcnt(8)" ::: "memory");
    __builtin_amdgcn_s_barrier();
    asm volatile("s_waitcnt lgkmcnt(0)" ::: "memory");
    __builtin_amdgcn_sched_barrier(0);
    __builtin_amdgcn_s_setprio(1);
    MFMA_QUAD(0, 0, a0, b0)
    __builtin_amdgcn_s_setprio(0);
    __builtin_amdgcn_s_barrier();

    // ---------- P2: read B-n1 (4); mfma (m0,n1)
#pragma unroll
    for (int nn = 0; nn < 2; ++nn)
#pragma unroll
      for (int ks = 0; ks < 2; ++ks)
        b1[nn][ks] = *reinterpret_cast<const bf16x8*>(
            bufc + bSub[1][nn] + ks * 1024 + rsw);
    __builtin_amdgcn_s_barrier();
    asm volatile("s_waitcnt lgkmcnt(0)" ::: "memory");
    __builtin_amdgcn_sched_barrier(0);
    __builtin_amdgcn_s_setprio(1);
    MFMA_QUAD(0, 2, a0, b1)
    __builtin_amdgcn_s_setprio(0);
    __builtin_amdgcn_s_barrier();

    // ---------- P3: read A-m1 (8); stage B0,B1(t+2) into bufc (B reads done at P2);
    //             mfma (m1,n1)
#pragma unroll
    for (int mm = 0; mm < 4; ++mm)
#pragma unroll
      for (int ks = 0; ks < 2; ++ks)
        a1[mm][ks] = *reinterpret_cast<const bf16x8*>(
            bufc + aBase + ((4 + mm) * 2 + ks) * 1024 + rsw);
    if (t + 2 < NT) {
      const int kb = k0B + (t + 2) * 128;
      stage_half(B, rowB0,       ldb, kb, bufc + 32768, tid);
      stage_half(B, rowB0 + 128, ldb, kb, bufc + 49152, tid);
    }
    __builtin_amdgcn_s_barrier();
    asm volatile("s_waitcnt lgkmcnt(0)" ::: "memory");
    __builtin_amdgcn_sched_barrier(0);
    __builtin_amdgcn_s_setprio(1);
    MFMA_QUAD(4, 2, a1, b1)
    __builtin_amdgcn_s_setprio(0);
    __builtin_amdgcn_s_barrier();

    // ---------- P4: stage A0,A1(t+2) into bufc (A reads done at P3);
    //             vmcnt(8) retires tile t+1's 8 loads; mfma (m1,n0)
    if (t + 2 < NT) {
      const int kb = k0B + (t + 2) * 128;
      stage_half(A, rowA0,       lda, kb, bufc + 0,     tid);
      stage_half(A, rowA0 + 128, lda, kb, bufc + 16384, tid);
      asm volatile("s_waitcnt vmcnt(8)" ::: "memory");
    } else {
      asm volatile("s_waitcnt vmcnt(0)" ::: "memory");
    }
    __builtin_amdgcn_sched_barrier(0);
    __builtin_amdgcn_s_barrier();
    __builtin_amdgcn_s_setprio(1);
    MFMA_QUAD(4, 0, a1, b0)
    __builtin_amdgcn_s_setprio(0);
    __builtin_amdgcn_s_barrier();
  }

  // ---------- epilogue: C/D frag mapping col=lane&15, row=(lane>>4)*4+reg
  const int r0 = rowA0 + wm * 128;
  const int c0 = rowB0 + wn * 64;
#pragma unroll
  for (int mi = 0; mi < 8; ++mi) {
    const int row = r0 + (mi >> 2) * 64 + (mi & 3) * 16 + kg * 4;
#pragma unroll
    for (int ni = 0; ni < 4; ++ni) {
      const int col = c0 + (ni >> 1) * 32 + (ni & 1) * 16 + l15;
      f32x4 v = acc[mi][ni];
      if constexpr (EPI == EPI_F32) {
#pragma unroll
        for (int r = 0; r < 4; ++r)
          Cf[(size_t)(row + r) * ldc + col] = v[r];
      } else if constexpr (EPI == EPI_BF16) {
#pragma unroll
        for (int r = 0; r < 4; ++r)
          Cb[(size_t)(row + r) * ldc + col] = f2bf(v[r] * scale);
      } else {  // EPI_QKV: cols<4096 -> qkb [4096][4096]; cols>=4096 -> vt transposed
        if (rowB0 < 4096) {
#pragma unroll
          for (int r = 0; r < 4; ++r)
            Cb[(size_t)(row + r) * 4096 + col] = f2bf(v[r]);
        } else {
          ushort4 pk;
          pk.x = f2bf(v[0]); pk.y = f2bf(v[1]);
          pk.z = f2bf(v[2]); pk.w = f2bf(v[3]);
          *reinterpret_cast<ushort4*>(Ct + (size_t)(col - 4096) * 4096 + row) = pk;
        }
      }
    }
  }
}

// ---------------- row softmax: S (bf16 [4096][4096]) -> P (bf16) ----------------
__global__ __launch_bounds__(256) void softmax_kernel(const unsigned short* __restrict__ Sm,
                                                      unsigned short* __restrict__ P) {
  const int row = blockIdx.x;
  const int tid = threadIdx.x;
  const unsigned short* src = Sm + (size_t)row * S_DIM;
  float vals[16];
  float mx = -1e30f;
#pragma unroll
  for (int i = 0; i < 4; ++i) {
    ushort4 h = reinterpret_cast<const ushort4*>(src)[tid + i * 256];
    float a = bf2f(h.x), b = bf2f(h.y), c = bf2f(h.z), d = bf2f(h.w);
    vals[i * 4 + 0] = a; vals[i * 4 + 1] = b;
    vals[i * 4 + 2] = c; vals[i * 4 + 3] = d;
    mx = fmaxf(mx, fmaxf(fmaxf(a, b), fmaxf(c, d)));
  }
#pragma unroll
  for (int off = 32; off >= 1; off >>= 1) mx = fmaxf(mx, __shfl_xor(mx, off, 64));
  __shared__ float red[8];
  const int wave = tid >> 6, lane = tid & 63;
  if (lane == 0) red[wave] = mx;
  __syncthreads();
  mx = fmaxf(fmaxf(red[0], red[1]), fmaxf(red[2], red[3]));
  float sum = 0.f;
#pragma unroll
  for (int i = 0; i < 16; ++i) { vals[i] = __expf(vals[i] - mx); sum += vals[i]; }
#pragma unroll
  for (int off = 32; off >= 1; off >>= 1) sum += __shfl_xor(sum, off, 64);
  if (lane == 0) red[4 + wave] = sum;
  __syncthreads();
  sum = red[4] + red[5] + red[6] + red[7];
  const float inv = 1.0f / sum;
  unsigned short* dst = P + (size_t)row * S_DIM;
#pragma unroll
  for (int i = 0; i < 4; ++i) {
    ushort4 pk;
    pk.x = f2bf(vals[i * 4 + 0] * inv);
    pk.y = f2bf(vals[i * 4 + 1] * inv);
    pk.z = f2bf(vals[i * 4 + 2] * inv);
    pk.w = f2bf(vals[i * 4 + 3] * inv);
    reinterpret_cast<ushort4*>(dst)[tid + i * 256] = pk;
  }
}

extern "C" void kernel_launch(void* const* d_in, const int* in_sizes, int n_in,
                              void* d_out, int out_size, void* d_ws, size_t ws_size,
                              hipStream_t stream) {
  const float* x  = (const float*)d_in[0];
  const float* Wq = (const float*)d_in[1];
  const float* Wk = (const float*)d_in[2];
  const float* Wv = (const float*)d_in[3];
  float* out = (float*)d_out;
  char* ws = (char*)d_ws;

  const size_t MB = 1024 * 1024;
  const size_t NEED = 120 * MB;
  if (ws_size < NEED) return;  // visible absmax failure instead of OOB crash

  // Layout (120 MiB):
  //   [0,16)   xb bf16 [4096][2048]     }-> outp0 f32 [4096][2048] at PV
  //   [16,40)  wcat bf16 [6144][2048]   }   (xb+wcat dead after proj)
  //   [40,72)  qkb bf16 [4096][4096] (Q cols 0-2047, K cols 2048-4095) -> P after QK
  //   [72,88)  vt bf16 [2048][4096]
  //   [88,120) Sb bf16 [4096][4096]     -> outp1 f32 at PV (over dead Sb)
  unsigned short* xb   = (unsigned short*)(ws);
  unsigned short* wcat = (unsigned short*)(ws + 16 * MB);
  unsigned short* qkb  = (unsigned short*)(ws + 40 * MB);
  unsigned short* vt   = (unsigned short*)(ws + 72 * MB);
  unsigned short* Sb   = (unsigned short*)(ws + 88 * MB);
  float* outp0 = (float*)(ws);
  float* outp1 = (float*)(ws + 88 * MB);
  unsigned short* P = qkb;

  // allow 128 KiB dynamic LDS (host-side attribute; graph-capture-safe)
  hipFuncSetAttribute(reinterpret_cast<const void*>(&gemm8<EPI_QKV>),
                      hipFuncAttributeMaxDynamicSharedMemorySize, 131072);
  hipFuncSetAttribute(reinterpret_cast<const void*>(&gemm8<EPI_BF16>),
                      hipFuncAttributeMaxDynamicSharedMemorySize, 131072);
  hipFuncSetAttribute(reinterpret_cast<const void*>(&gemm8<EPI_F32>),
                      hipFuncAttributeMaxDynamicSharedMemorySize, 131072);

  const int nx4 = S_DIM * E_DIM / 4;
  const int nw4 = E_DIM * E_DIM / 4;

  // 1) casts: x -> xb; Wq/Wk/Wv -> wcat rows 0/2048/4096 (one dispatch)
  cast_kernel<<<nx4 / 256, 256, 0, stream>>>(x, xb, nx4);
  cast3_kernel<<<3 * nw4 / 256, 256, 0, stream>>>(Wq, Wk, Wv, wcat, nw4);

  // 2) fused QKV projection: [4096][6144] = xb @ wcat^T; V-range written transposed
  gemm8<EPI_QKV><<<dim3(24, 16, 1), 512, 131072, stream>>>(
      xb, wcat, E_DIM, E_DIM, E_DIM, nullptr, qkb, vt, 4096, 1.0f, 0, 0);

  // 3) S = (Q @ K^T) * 1/sqrt(E) -> bf16
  const float scale = 0.022097086912079608f;
  gemm8<EPI_BF16><<<dim3(16, 16, 1), 512, 131072, stream>>>(
      qkb, qkb + 2048, 4096, 4096, E_DIM, nullptr, Sb, nullptr, 4096, scale, 0, 0);

  // 4) softmax -> P (aliases dead qkb)
  softmax_kernel<<<S_DIM, 256, 0, stream>>>(Sb, P);

  // 5) PV split-K=2: out_z = P[:, z*2048:+2048] @ vt[:, z*2048:+2048]^T
  gemm8<EPI_F32><<<dim3(8, 16, 2), 512, 131072, stream>>>(
      P, vt, 4096, 4096, 2048, outp0, nullptr, nullptr, E_DIM, 1.0f,
      2048, (long long)(88 * MB) / 4);

  // 6) out = outp0 + outp1
  add_kernel<<<nx4 / 256, 256, 0, stream>>>(outp0, outp1, out, nx4);
}

// Round 8
// 403.501 us; speedup vs baseline: 1.7964x; 1.0022x over previous
//
#include <hip/hip_runtime.h>
#include <hip/hip_bf16.h>

#define S_DIM 4096
#define E_DIM 2048

typedef __attribute__((ext_vector_type(4))) float f32x4;
typedef __attribute__((ext_vector_type(8))) short bf16x8;

__device__ __forceinline__ unsigned short f2bf(float f) {
  unsigned u = __builtin_bit_cast(unsigned, f);
  u += 0x7FFFu + ((u >> 16) & 1u);   // RNE
  return (unsigned short)(u >> 16);
}
__device__ __forceinline__ float bf2f(unsigned short h) {
  return __builtin_bit_cast(float, ((unsigned)h) << 16);
}

// ---------------- cast f32 -> bf16 ----------------
__global__ __launch_bounds__(256) void cast_kernel(const float* __restrict__ in,
                                                   unsigned short* __restrict__ out,
                                                   int n4) {
  int i = blockIdx.x * 256 + threadIdx.x;
  if (i >= n4) return;
  float4 v = reinterpret_cast<const float4*>(in)[i];
  ushort4 o;
  o.x = f2bf(v.x); o.y = f2bf(v.y); o.z = f2bf(v.z); o.w = f2bf(v.w);
  reinterpret_cast<ushort4*>(out)[i] = o;
}

// cast 3 weight matrices into concatenated wcat in one dispatch
__global__ __launch_bounds__(256) void cast3_kernel(const float* __restrict__ w0,
                                                    const float* __restrict__ w1,
                                                    const float* __restrict__ w2,
                                                    unsigned short* __restrict__ out,
                                                    int n4each) {
  int i = blockIdx.x * 256 + threadIdx.x;
  if (i >= 3 * n4each) return;
  const float* src = (i < n4each) ? w0 : (i < 2 * n4each ? w1 : w2);
  int j = (i < n4each) ? i : (i < 2 * n4each ? i - n4each : i - 2 * n4each);
  float4 v = reinterpret_cast<const float4*>(src)[j];
  ushort4 o;
  o.x = f2bf(v.x); o.y = f2bf(v.y); o.z = f2bf(v.z); o.w = f2bf(v.w);
  reinterpret_cast<ushort4*>(out)[i] = o;
}

// ---------------- add f32 partials ----------------
__global__ __launch_bounds__(256) void add_kernel(const float* __restrict__ a,
                                                  const float* __restrict__ b,
                                                  float* __restrict__ o, int n4) {
  int i = blockIdx.x * 256 + threadIdx.x;
  if (i >= n4) return;
  float4 va = reinterpret_cast<const float4*>(a)[i];
  float4 vb = reinterpret_cast<const float4*>(b)[i];
  float4 vo = {va.x + vb.x, va.y + vb.y, va.z + vb.z, va.w + vb.w};
  reinterpret_cast<float4*>(o)[i] = vo;
}

// ======================= 8-phase 256x256 NT GEMM (bf16) =======================
// C = A @ B^T.  BM=BN=256, BK=64, 512 threads = 8 waves (2M x 4N).
// Register software-pipeline: quadrants P1(m0n0) P2(m0n1) P3(m1n1) P4(m1n0);
// ds_reads issued >=1 phase before consumption, counted lgkm waits:
//   P1 loads b1 -> wait lgkm(4)  (a0,b0 loaded last tile's P4)
//   P2 loads a1 -> wait lgkm(8)  (b1 from P1)
//   P3 stage B(t+2), vmcnt(4), entry-bar certifies t+1 stages landed; wait lgkm(0)
//   P4 loads a0'(t+1) + stage A(t+2); MFMA(m1,n0); then loads b0'(t+1)
// vmcnt never drains below 4 mid-loop; st_16x32 LDS swizzle throughout.

__device__ __forceinline__ void stage_half(const unsigned short* __restrict__ g,
                                           int grow0, int ld, int kByte0,
                                           char* ldsHalfBase, int tid) {
#pragma unroll
  for (int p = 0; p < 2; ++p) {
    const int o = (p * 512 + tid) * 16;            // linear LDS byte offset
    const int S = o >> 10;                         // subtile 0..15
    const int oi = o & 1023;
    const int osi = oi ^ (((oi >> 9) & 1) << 5);   // inverse swizzle on source
    const int r  = (S >> 1) * 16 + (osi >> 6);     // row in half-tile 0..127
    const int cb = (S & 1) * 64 + (osi & 63);      // byte col 0..127
    const char* ga = reinterpret_cast<const char*>(g) +
                     ((size_t)(grow0 + r) * ld) * 2 + kByte0 + cb;
    char* la = ldsHalfBase + (o & ~1023);          // wave-uniform base; HW adds lane*16
    __builtin_amdgcn_global_load_lds(
        (const __attribute__((address_space(1))) void*)ga,
        (__attribute__((address_space(3))) void*)la, 16, 0, 0);
  }
}

#define MFMA_QUAD(AM, AN, AF, BF)                                              \
  _Pragma("unroll") for (int mm = 0; mm < 4; ++mm)                             \
  _Pragma("unroll") for (int nn = 0; nn < 2; ++nn)                             \
  _Pragma("unroll") for (int ks = 0; ks < 2; ++ks)                             \
    acc[(AM) + mm][(AN) + nn] = __builtin_amdgcn_mfma_f32_16x16x32_bf16(       \
        AF[mm][ks], BF[nn][ks], acc[(AM) + mm][(AN) + nn], 0, 0, 0);

#define READ_A0(dst, buf)                                                      \
  _Pragma("unroll") for (int mm = 0; mm < 4; ++mm)                             \
  _Pragma("unroll") for (int ks = 0; ks < 2; ++ks)                             \
    dst[mm][ks] = *reinterpret_cast<const bf16x8*>(                            \
        (buf) + aBase + (mm * 2 + ks) * 1024 + rsw);

#define READ_A1(dst, buf)                                                      \
  _Pragma("unroll") for (int mm = 0; mm < 4; ++mm)                             \
  _Pragma("unroll") for (int ks = 0; ks < 2; ++ks)                             \
    dst[mm][ks] = *reinterpret_cast<const bf16x8*>(                            \
        (buf) + aBase + ((4 + mm) * 2 + ks) * 1024 + rsw);

#define READ_B(dst, buf, nh)                                                   \
  _Pragma("unroll") for (int nn = 0; nn < 2; ++nn)                             \
  _Pragma("unroll") for (int ks = 0; ks < 2; ++ks)                             \
    dst[nn][ks] = *reinterpret_cast<const bf16x8*>(                            \
        (buf) + bSub[nh][nn] + ks * 1024 + rsw);

enum { EPI_QKV = 0, EPI_BF16 = 1, EPI_F32 = 2 };

template <int EPI>
__global__ __launch_bounds__(512, 2) void gemm8(
    const unsigned short* __restrict__ A, const unsigned short* __restrict__ B,
    int lda, int ldb, int K,
    float* __restrict__ Cf, unsigned short* __restrict__ Cb,
    unsigned short* __restrict__ Ct, int ldc, float scale,
    int kElemPerZ, long long zStrideC) {
  extern __shared__ char lds[];

  const int tid = threadIdx.x;
  const int rowA0 = blockIdx.y * 256;   // natural mapping: bx%8 = XCD -> B-panel L2 reuse
  const int rowB0 = blockIdx.x * 256;
  const int k0B = blockIdx.z * kElemPerZ * 2;   // k byte offset for this z-slice
  if (EPI == EPI_F32) Cf += (size_t)blockIdx.z * zStrideC;

  const int wave = tid >> 6;
  const int lane = tid & 63;
  const int wm = wave >> 2;   // 0..1 (M)
  const int wn = wave & 3;    // 0..3 (N)
  const int l15 = lane & 15;
  const int kg = lane >> 4;
  const int rsw = (l15 * 64 + kg * 16) ^ ((l15 & 8) << 2);  // swizzled in-subtile off

  int bSub[2][2];
#pragma unroll
  for (int nh = 0; nh < 2; ++nh)
#pragma unroll
    for (int nn = 0; nn < 2; ++nn) {
      const int row = wn * 64 + nh * 32 + nn * 16;
      bSub[nh][nn] = 32768 + (row >> 7) * 16384 + ((row & 127) >> 4) * 2048;
    }
  const int aBase = wm * 16384;

  f32x4 acc[8][4];
#pragma unroll
  for (int mi = 0; mi < 8; ++mi)
#pragma unroll
    for (int ni = 0; ni < 4; ++ni) acc[mi][ni] = (f32x4){0.f, 0.f, 0.f, 0.f};

  const int NT = K / 64;
  char* buf0 = lds;
  char* buf1 = lds + 65536;

  // ---- prologue: stage tile0 + tile1 (16 loads/thread); retire tile0; read a0,b0
  stage_half(A, rowA0,       lda, k0B,       buf0 + 0,     tid);
  stage_half(A, rowA0 + 128, lda, k0B,       buf0 + 16384, tid);
  stage_half(B, rowB0,       ldb, k0B,       buf0 + 32768, tid);
  stage_half(B, rowB0 + 128, ldb, k0B,       buf0 + 49152, tid);
  stage_half(A, rowA0,       lda, k0B + 128, buf1 + 0,     tid);
  stage_half(A, rowA0 + 128, lda, k0B + 128, buf1 + 16384, tid);
  stage_half(B, rowB0,       ldb, k0B + 128, buf1 + 32768, tid);
  stage_half(B, rowB0 + 128, ldb, k0B + 128, buf1 + 49152, tid);
  asm volatile("s_waitcnt vmcnt(8)" ::: "memory");
  __builtin_amdgcn_sched_barrier(0);
  __builtin_amdgcn_s_barrier();   // all waves' tile0 stages landed

  bf16x8 a0[4][2], a1[4][2], b0[2][2], b1[2][2];
  READ_A0(a0, buf0)
  READ_B(b0, buf0, 0)
  __builtin_amdgcn_sched_barrier(0);

  for (int t = 0; t < NT; ++t) {
    char* bufc = lds + (t & 1) * 65536;
    char* bufn = lds + ((t & 1) ^ 1) * 65536;

    // ---------- P1: load b1(t); wait a0,b0; MFMA (m0,n0)
    READ_B(b1, bufc, 1)
    __builtin_amdgcn_s_barrier();
    asm volatile("s_waitcnt lgkmcnt(4)" ::: "memory");
    __builtin_amdgcn_sched_barrier(0);
    __builtin_amdgcn_s_setprio(1);
    MFMA_QUAD(0, 0, a0, b0)
    __builtin_amdgcn_s_setprio(0);
    __builtin_amdgcn_s_barrier();

    // ---------- P2: load a1(t); wait b1; MFMA (m0,n1)
    READ_A1(a1, bufc)
    __builtin_amdgcn_s_barrier();
    asm volatile("s_waitcnt lgkmcnt(8)" ::: "memory");
    __builtin_amdgcn_sched_barrier(0);
    __builtin_amdgcn_s_setprio(1);
    MFMA_QUAD(0, 2, a0, b1)
    __builtin_amdgcn_s_setprio(0);
    __builtin_amdgcn_s_barrier();

    // ---------- P3: stage B(t+2) into bufc; vmcnt(4) retires t+1's stages;
    //             entry-bar certifies them landed for ALL waves; wait a1; MFMA (m1,n1)
    if (t + 2 < NT) {
      const int kb = k0B + (t + 2) * 128;
      stage_half(B, rowB0,       ldb, kb, bufc + 32768, tid);
      stage_half(B, rowB0 + 128, ldb, kb, bufc + 49152, tid);
      asm volatile("s_waitcnt vmcnt(4)" ::: "memory");
    } else if (t + 1 < NT) {
      asm volatile("s_waitcnt vmcnt(0)" ::: "memory");
    }
    __builtin_amdgcn_sched_barrier(0);
    __builtin_amdgcn_s_barrier();
    asm volatile("s_waitcnt lgkmcnt(0)" ::: "memory");
    __builtin_amdgcn_sched_barrier(0);
    __builtin_amdgcn_s_setprio(1);
    MFMA_QUAD(4, 2, a1, b1)
    __builtin_amdgcn_s_setprio(0);
    __builtin_amdgcn_s_barrier();

    // ---------- P4: load a0'(t+1) from bufn (safe: P3 bar after vmcnt);
    //             stage A(t+2); MFMA (m1,n0); then load b0'(t+1)
    if (t + 1 < NT) { READ_A0(a0, bufn) }
    if (t + 2 < NT) {
      const int kb = k0B + (t + 2) * 128;
      stage_half(A, rowA0,       lda, kb, bufc + 0,     tid);
      stage_half(A, rowA0 + 128, lda, kb, bufc + 16384, tid);
    }
    __builtin_amdgcn_sched_barrier(0);
    __builtin_amdgcn_s_barrier();
    __builtin_amdgcn_s_setprio(1);
    MFMA_QUAD(4, 0, a1, b0)
    __builtin_amdgcn_s_setprio(0);
    __builtin_amdgcn_sched_barrier(0);
    if (t + 1 < NT) { READ_B(b0, bufn, 0) }
    __builtin_amdgcn_sched_barrier(0);
    __builtin_amdgcn_s_barrier();
  }

  // ---------- epilogue: C/D frag mapping col=lane&15, row=(lane>>4)*4+reg
  const int r0 = rowA0 + wm * 128;
  const int c0 = rowB0 + wn * 64;
#pragma unroll
  for (int mi = 0; mi < 8; ++mi) {
    const int row = r0 + (mi >> 2) * 64 + (mi & 3) * 16 + kg * 4;
#pragma unroll
    for (int ni = 0; ni < 4; ++ni) {
      const int col = c0 + (ni >> 1) * 32 + (ni & 1) * 16 + l15;
      f32x4 v = acc[mi][ni];
      if constexpr (EPI == EPI_F32) {
#pragma unroll
        for (int r = 0; r < 4; ++r)
          Cf[(size_t)(row + r) * ldc + col] = v[r];
      } else if constexpr (EPI == EPI_BF16) {
#pragma unroll
        for (int r = 0; r < 4; ++r)
          Cb[(size_t)(row + r) * ldc + col] = f2bf(v[r] * scale);
      } else {  // EPI_QKV: cols<4096 -> qkb [4096][4096]; cols>=4096 -> vt transposed
        if (rowB0 < 4096) {
#pragma unroll
          for (int r = 0; r < 4; ++r)
            Cb[(size_t)(row + r) * 4096 + col] = f2bf(v[r]);
        } else {
          ushort4 pk;
          pk.x = f2bf(v[0]); pk.y = f2bf(v[1]);
          pk.z = f2bf(v[2]); pk.w = f2bf(v[3]);
          *reinterpret_cast<ushort4*>(Ct + (size_t)(col - 4096) * 4096 + row) = pk;
        }
      }
    }
  }
}

// ---------------- row softmax: S (bf16 [4096][4096]) -> P (bf16) ----------------
__global__ __launch_bounds__(256) void softmax_kernel(const unsigned short* __restrict__ Sm,
                                                      unsigned short* __restrict__ P) {
  const int row = blockIdx.x;
  const int tid = threadIdx.x;
  const unsigned short* src = Sm + (size_t)row * S_DIM;
  float vals[16];
  float mx = -1e30f;
#pragma unroll
  for (int i = 0; i < 4; ++i) {
    ushort4 h = reinterpret_cast<const ushort4*>(src)[tid + i * 256];
    float a = bf2f(h.x), b = bf2f(h.y), c = bf2f(h.z), d = bf2f(h.w);
    vals[i * 4 + 0] = a; vals[i * 4 + 1] = b;
    vals[i * 4 + 2] = c; vals[i * 4 + 3] = d;
    mx = fmaxf(mx, fmaxf(fmaxf(a, b), fmaxf(c, d)));
  }
#pragma unroll
  for (int off = 32; off >= 1; off >>= 1) mx = fmaxf(mx, __shfl_xor(mx, off, 64));
  __shared__ float red[8];
  const int wave = tid >> 6, lane = tid & 63;
  if (lane == 0) red[wave] = mx;
  __syncthreads();
  mx = fmaxf(fmaxf(red[0], red[1]), fmaxf(red[2], red[3]));
  float sum = 0.f;
#pragma unroll
  for (int i = 0; i < 16; ++i) { vals[i] = __expf(vals[i] - mx); sum += vals[i]; }
#pragma unroll
  for (int off = 32; off >= 1; off >>= 1) sum += __shfl_xor(sum, off, 64);
  if (lane == 0) red[4 + wave] = sum;
  __syncthreads();
  sum = red[4] + red[5] + red[6] + red[7];
  const float inv = 1.0f / sum;
  unsigned short* dst = P + (size_t)row * S_DIM;
#pragma unroll
  for (int i = 0; i < 4; ++i) {
    ushort4 pk;
    pk.x = f2bf(vals[i * 4 + 0] * inv);
    pk.y = f2bf(vals[i * 4 + 1] * inv);
    pk.z = f2bf(vals[i * 4 + 2] * inv);
    pk.w = f2bf(vals[i * 4 + 3] * inv);
    reinterpret_cast<ushort4*>(dst)[tid + i * 256] = pk;
  }
}

extern "C" void kernel_launch(void* const* d_in, const int* in_sizes, int n_in,
                              void* d_out, int out_size, void* d_ws, size_t ws_size,
                              hipStream_t stream) {
  const float* x  = (const float*)d_in[0];
  const float* Wq = (const float*)d_in[1];
  const float* Wk = (const float*)d_in[2];
  const float* Wv = (const float*)d_in[3];
  float* out = (float*)d_out;
  char* ws = (char*)d_ws;

  const size_t MB = 1024 * 1024;
  const size_t NEED = 120 * MB;
  if (ws_size < NEED) return;  // visible absmax failure instead of OOB crash

  // Layout (120 MiB):
  //   [0,16)   xb bf16 [4096][2048]     }-> outp0 f32 [4096][2048] at PV
  //   [16,40)  wcat bf16 [6144][2048]   }   (xb+wcat dead after proj)
  //   [40,72)  qkb bf16 [4096][4096] (Q cols 0-2047, K cols 2048-4095) -> P after QK
  //   [72,88)  vt bf16 [2048][4096]
  //   [88,120) Sb bf16 [4096][4096]     -> outp1 f32 at PV (over dead Sb)
  unsigned short* xb   = (unsigned short*)(ws);
  unsigned short* wcat = (unsigned short*)(ws + 16 * MB);
  unsigned short* qkb  = (unsigned short*)(ws + 40 * MB);
  unsigned short* vt   = (unsigned short*)(ws + 72 * MB);
  unsigned short* Sb   = (unsigned short*)(ws + 88 * MB);
  float* outp0 = (float*)(ws);
  float* outp1 = (float*)(ws + 88 * MB);
  unsigned short* P = qkb;

  // allow 128 KiB dynamic LDS (host-side attribute; graph-capture-safe)
  hipFuncSetAttribute(reinterpret_cast<const void*>(&gemm8<EPI_QKV>),
                      hipFuncAttributeMaxDynamicSharedMemorySize, 131072);
  hipFuncSetAttribute(reinterpret_cast<const void*>(&gemm8<EPI_BF16>),
                      hipFuncAttributeMaxDynamicSharedMemorySize, 131072);
  hipFuncSetAttribute(reinterpret_cast<const void*>(&gemm8<EPI_F32>),
                      hipFuncAttributeMaxDynamicSharedMemorySize, 131072);

  const int nx4 = S_DIM * E_DIM / 4;
  const int nw4 = E_DIM * E_DIM / 4;

  // 1) casts: x -> xb; Wq/Wk/Wv -> wcat rows 0/2048/4096 (one dispatch)
  cast_kernel<<<nx4 / 256, 256, 0, stream>>>(x, xb, nx4);
  cast3_kernel<<<3 * nw4 / 256, 256, 0, stream>>>(Wq, Wk, Wv, wcat, nw4);

  // 2) fused QKV projection: [4096][6144] = xb @ wcat^T; V-range written transposed
  gemm8<EPI_QKV><<<dim3(24, 16, 1), 512, 131072, stream>>>(
      xb, wcat, E_DIM, E_DIM, E_DIM, nullptr, qkb, vt, 4096, 1.0f, 0, 0);

  // 3) S = (Q @ K^T) * 1/sqrt(E) -> bf16
  const float scale = 0.022097086912079608f;
  gemm8<EPI_BF16><<<dim3(16, 16, 1), 512, 131072, stream>>>(
      qkb, qkb + 2048, 4096, 4096, E_DIM, nullptr, Sb, nullptr, 4096, scale, 0, 0);

  // 4) softmax -> P (aliases dead qkb)
  softmax_kernel<<<S_DIM, 256, 0, stream>>>(Sb, P);

  // 5) PV split-K=2: out_z = P[:, z*2048:+2048] @ vt[:, z*2048:+2048]^T
  gemm8<EPI_F32><<<dim3(8, 16, 2), 512, 131072, stream>>>(
      P, vt, 4096, 4096, 2048, outp0, nullptr, nullptr, E_DIM, 1.0f,
      2048, (long long)(88 * MB) / 4);

  // 6) out = outp0 + outp1
  add_kernel<<<nx4 / 256, 256, 0, stream>>>(outp0, outp1, out, nx4);
}

// Round 9
// 398.103 us; speedup vs baseline: 1.8208x; 1.0136x over previous
//
#include <hip/hip_runtime.h>
#include <hip/hip_bf16.h>

#define S_DIM 4096
#define E_DIM 2048

typedef __attribute__((ext_vector_type(4))) float f32x4;
typedef __attribute__((ext_vector_type(8))) short bf16x8;

__device__ __forceinline__ unsigned short f2bf(float f) {
  unsigned u = __builtin_bit_cast(unsigned, f);
  u += 0x7FFFu + ((u >> 16) & 1u);   // RNE
  return (unsigned short)(u >> 16);
}
__device__ __forceinline__ float bf2f(unsigned short h) {
  return __builtin_bit_cast(float, ((unsigned)h) << 16);
}

// ---------------- cast f32 -> bf16 ----------------
__global__ __launch_bounds__(256) void cast_kernel(const float* __restrict__ in,
                                                   unsigned short* __restrict__ out,
                                                   int n4) {
  int i = blockIdx.x * 256 + threadIdx.x;
  if (i >= n4) return;
  float4 v = reinterpret_cast<const float4*>(in)[i];
  ushort4 o;
  o.x = f2bf(v.x); o.y = f2bf(v.y); o.z = f2bf(v.z); o.w = f2bf(v.w);
  reinterpret_cast<ushort4*>(out)[i] = o;
}

// cast 3 weight matrices into concatenated wcat in one dispatch
__global__ __launch_bounds__(256) void cast3_kernel(const float* __restrict__ w0,
                                                    const float* __restrict__ w1,
                                                    const float* __restrict__ w2,
                                                    unsigned short* __restrict__ out,
                                                    int n4each) {
  int i = blockIdx.x * 256 + threadIdx.x;
  if (i >= 3 * n4each) return;
  const float* src = (i < n4each) ? w0 : (i < 2 * n4each ? w1 : w2);
  int j = (i < n4each) ? i : (i < 2 * n4each ? i - n4each : i - 2 * n4each);
  float4 v = reinterpret_cast<const float4*>(src)[j];
  ushort4 o;
  o.x = f2bf(v.x); o.y = f2bf(v.y); o.z = f2bf(v.z); o.w = f2bf(v.w);
  reinterpret_cast<ushort4*>(out)[i] = o;
}

// ---------------- add f32 partials ----------------
__global__ __launch_bounds__(256) void add_kernel(const float* __restrict__ a,
                                                  const float* __restrict__ b,
                                                  float* __restrict__ o, int n4) {
  int i = blockIdx.x * 256 + threadIdx.x;
  if (i >= n4) return;
  float4 va = reinterpret_cast<const float4*>(a)[i];
  float4 vb = reinterpret_cast<const float4*>(b)[i];
  float4 vo = {va.x + vb.x, va.y + vb.y, va.z + vb.z, va.w + vb.w};
  reinterpret_cast<float4*>(o)[i] = vo;
}

// ======================= 2-phase 256x256 NT GEMM (bf16) =======================
// C = A @ B^T.  BM=BN=256, BK=64, 512 threads = 8 waves (2M x 4N).
// TWO phases per K-tile (32 MFMA each) -> 4 barriers/tile (was 8).
//   PA(t): read a0(8),b0(4),b1(4); stage A1(t+1); bar; lgkm0; 32 MFMA (m0 x n0..n3)
//   PB(t): read a1(8); stage B0,B1,A0(t+2); vmcnt(6); bar; lgkm0; 32 MFMA (m1 x n0..n3)
// Liveness (ring-2): A1(t+1) target last read at PB(t-1) [certified]; B/A0(t+2)
// targets last read at PA(t) [certified]. vmcnt(6) at PB retires exactly tile
// t+1 (A1(t+1)[2] + B,A0(t+2)[6] outstanding = 8 -> wait 6 retires oldest 2);
// never drains to 0 mid-loop. MFMA ks-outer: dep distance 16 on each acc.
// st_16x32 LDS swizzle; linear gload_lds dest + inverse-swizzled global src.

__device__ __forceinline__ void stage_half(const unsigned short* __restrict__ g,
                                           int grow0, int ld, int kByte0,
                                           char* ldsHalfBase, int tid) {
#pragma unroll
  for (int p = 0; p < 2; ++p) {
    const int o = (p * 512 + tid) * 16;            // linear LDS byte offset
    const int S = o >> 10;                         // subtile 0..15
    const int oi = o & 1023;
    const int osi = oi ^ (((oi >> 9) & 1) << 5);   // inverse swizzle on source
    const int r  = (S >> 1) * 16 + (osi >> 6);     // row in half-tile 0..127
    const int cb = (S & 1) * 64 + (osi & 63);      // byte col 0..127
    const char* ga = reinterpret_cast<const char*>(g) +
                     ((size_t)(grow0 + r) * ld) * 2 + kByte0 + cb;
    char* la = ldsHalfBase + (o & ~1023);          // wave-uniform base; HW adds lane*16
    __builtin_amdgcn_global_load_lds(
        (const __attribute__((address_space(1))) void*)ga,
        (__attribute__((address_space(3))) void*)la, 16, 0, 0);
  }
}

// 32 MFMA covering one M-half (4 m-frags) x full N (4 n-frags) x K=64 (2 ks).
// ks-outer: 16 independent MFMAs between the two writes to each acc.
#define MFMA_HALF(AM, AF)                                                      \
  _Pragma("unroll") for (int ks = 0; ks < 2; ++ks)                             \
  _Pragma("unroll") for (int mm = 0; mm < 4; ++mm) {                           \
    acc[(AM) + mm][0] = __builtin_amdgcn_mfma_f32_16x16x32_bf16(               \
        AF[mm][ks], b0[0][ks], acc[(AM) + mm][0], 0, 0, 0);                    \
    acc[(AM) + mm][1] = __builtin_amdgcn_mfma_f32_16x16x32_bf16(               \
        AF[mm][ks], b0[1][ks], acc[(AM) + mm][1], 0, 0, 0);                    \
    acc[(AM) + mm][2] = __builtin_amdgcn_mfma_f32_16x16x32_bf16(               \
        AF[mm][ks], b1[0][ks], acc[(AM) + mm][2], 0, 0, 0);                    \
    acc[(AM) + mm][3] = __builtin_amdgcn_mfma_f32_16x16x32_bf16(               \
        AF[mm][ks], b1[1][ks], acc[(AM) + mm][3], 0, 0, 0);                    \
  }

#define READ_A0(dst, buf)                                                      \
  _Pragma("unroll") for (int mm = 0; mm < 4; ++mm)                             \
  _Pragma("unroll") for (int ks = 0; ks < 2; ++ks)                             \
    dst[mm][ks] = *reinterpret_cast<const bf16x8*>(                            \
        (buf) + aBase + (mm * 2 + ks) * 1024 + rsw);

#define READ_A1(dst, buf)                                                      \
  _Pragma("unroll") for (int mm = 0; mm < 4; ++mm)                             \
  _Pragma("unroll") for (int ks = 0; ks < 2; ++ks)                             \
    dst[mm][ks] = *reinterpret_cast<const bf16x8*>(                            \
        (buf) + aBase + ((4 + mm) * 2 + ks) * 1024 + rsw);

#define READ_B(dst, buf, nh)                                                   \
  _Pragma("unroll") for (int nn = 0; nn < 2; ++nn)                             \
  _Pragma("unroll") for (int ks = 0; ks < 2; ++ks)                             \
    dst[nn][ks] = *reinterpret_cast<const bf16x8*>(                            \
        (buf) + bSub[nh][nn] + ks * 1024 + rsw);

enum { EPI_QKV = 0, EPI_BF16 = 1, EPI_F32 = 2 };

template <int EPI>
__global__ __launch_bounds__(512, 2) void gemm8(
    const unsigned short* __restrict__ A, const unsigned short* __restrict__ B,
    int lda, int ldb, int K,
    float* __restrict__ Cf, unsigned short* __restrict__ Cb,
    unsigned short* __restrict__ Ct, int ldc, float scale,
    int kElemPerZ, long long zStrideC) {
  extern __shared__ char lds[];

  const int tid = threadIdx.x;
  const int rowA0 = blockIdx.y * 256;   // natural mapping: bx%8 = XCD -> B-panel L2 reuse
  const int rowB0 = blockIdx.x * 256;
  const int k0B = blockIdx.z * kElemPerZ * 2;   // k byte offset for this z-slice
  if (EPI == EPI_F32) Cf += (size_t)blockIdx.z * zStrideC;

  const int wave = tid >> 6;
  const int lane = tid & 63;
  const int wm = wave >> 2;   // 0..1 (M)
  const int wn = wave & 3;    // 0..3 (N)
  const int l15 = lane & 15;
  const int kg = lane >> 4;
  const int rsw = (l15 * 64 + kg * 16) ^ ((l15 & 8) << 2);  // swizzled in-subtile off

  int bSub[2][2];
#pragma unroll
  for (int nh = 0; nh < 2; ++nh)
#pragma unroll
    for (int nn = 0; nn < 2; ++nn) {
      const int row = wn * 64 + nh * 32 + nn * 16;
      bSub[nh][nn] = 32768 + (row >> 7) * 16384 + ((row & 127) >> 4) * 2048;
    }
  const int aBase = wm * 16384;

  f32x4 acc[8][4];
#pragma unroll
  for (int mi = 0; mi < 8; ++mi)
#pragma unroll
    for (int ni = 0; ni < 4; ++ni) acc[mi][ni] = (f32x4){0.f, 0.f, 0.f, 0.f};

  const int NT = K / 64;
  char* buf0 = lds;
  char* buf1 = lds + 65536;

  // ---- prologue: tile0 fully (8), tile1 B+A0 (6); vmcnt(6) retires tile0.
  //      (t=0's PA stages A1(1), completing tile1 per steady state.)
  stage_half(B, rowB0,       ldb, k0B,       buf0 + 32768, tid);
  stage_half(B, rowB0 + 128, ldb, k0B,       buf0 + 49152, tid);
  stage_half(A, rowA0,       lda, k0B,       buf0 + 0,     tid);
  stage_half(A, rowA0 + 128, lda, k0B,       buf0 + 16384, tid);
  stage_half(B, rowB0,       ldb, k0B + 128, buf1 + 32768, tid);
  stage_half(B, rowB0 + 128, ldb, k0B + 128, buf1 + 49152, tid);
  stage_half(A, rowA0,       lda, k0B + 128, buf1 + 0,     tid);
  asm volatile("s_waitcnt vmcnt(6)" ::: "memory");
  __builtin_amdgcn_sched_barrier(0);
  __builtin_amdgcn_s_barrier();   // tile0 resident for all waves

  for (int t = 0; t < NT; ++t) {
    char* bufc = lds + (t & 1) * 65536;
    char* bufn = lds + ((t & 1) ^ 1) * 65536;
    bf16x8 a0[4][2], a1[4][2], b0[2][2], b1[2][2];

    // ---------- PA: read a0,b0,b1 (16); stage A1(t+1) -> bufn.A-hi
    //            (bufn.A-hi last read at PB(t-1), certified by its exit barrier)
    READ_A0(a0, bufc)
    READ_B(b0, bufc, 0)
    READ_B(b1, bufc, 1)
    if (t + 1 < NT)
      stage_half(A, rowA0 + 128, lda, k0B + (t + 1) * 128, bufn + 16384, tid);
    __builtin_amdgcn_sched_barrier(0);
    __builtin_amdgcn_s_barrier();
    asm volatile("s_waitcnt lgkmcnt(0)" ::: "memory");
    __builtin_amdgcn_sched_barrier(0);
    __builtin_amdgcn_s_setprio(1);
    MFMA_HALF(0, a0)
    __builtin_amdgcn_s_setprio(0);
    __builtin_amdgcn_s_barrier();

    // ---------- PB: read a1 (8); stage B0,B1,A0(t+2) -> bufc (those areas'
    //            reads happened in PA, certified by PA's exit barrier);
    //            vmcnt(6) retires tile t+1's loads; exit barrier certifies.
    READ_A1(a1, bufc)
    if (t + 2 < NT) {
      const int kb = k0B + (t + 2) * 128;
      stage_half(B, rowB0,       ldb, kb, bufc + 32768, tid);
      stage_half(B, rowB0 + 128, ldb, kb, bufc + 49152, tid);
      stage_half(A, rowA0,       lda, kb, bufc + 0,     tid);
      asm volatile("s_waitcnt vmcnt(6)" ::: "memory");
    } else {
      asm volatile("s_waitcnt vmcnt(0)" ::: "memory");
    }
    __builtin_amdgcn_sched_barrier(0);
    __builtin_amdgcn_s_barrier();
    asm volatile("s_waitcnt lgkmcnt(0)" ::: "memory");
    __builtin_amdgcn_sched_barrier(0);
    __builtin_amdgcn_s_setprio(1);
    MFMA_HALF(4, a1)
    __builtin_amdgcn_s_setprio(0);
    __builtin_amdgcn_s_barrier();
  }

  // ---------- epilogue: C/D frag mapping col=lane&15, row=(lane>>4)*4+reg
  const int r0 = rowA0 + wm * 128;
  const int c0 = rowB0 + wn * 64;
#pragma unroll
  for (int mi = 0; mi < 8; ++mi) {
    const int row = r0 + (mi >> 2) * 64 + (mi & 3) * 16 + kg * 4;
#pragma unroll
    for (int ni = 0; ni < 4; ++ni) {
      const int col = c0 + (ni >> 1) * 32 + (ni & 1) * 16 + l15;
      f32x4 v = acc[mi][ni];
      if constexpr (EPI == EPI_F32) {
#pragma unroll
        for (int r = 0; r < 4; ++r)
          Cf[(size_t)(row + r) * ldc + col] = v[r];
      } else if constexpr (EPI == EPI_BF16) {
#pragma unroll
        for (int r = 0; r < 4; ++r)
          Cb[(size_t)(row + r) * ldc + col] = f2bf(v[r] * scale);
      } else {  // EPI_QKV: cols<4096 -> qkb [4096][4096]; cols>=4096 -> vt transposed
        if (rowB0 < 4096) {
#pragma unroll
          for (int r = 0; r < 4; ++r)
            Cb[(size_t)(row + r) * 4096 + col] = f2bf(v[r]);
        } else {
          ushort4 pk;
          pk.x = f2bf(v[0]); pk.y = f2bf(v[1]);
          pk.z = f2bf(v[2]); pk.w = f2bf(v[3]);
          *reinterpret_cast<ushort4*>(Ct + (size_t)(col - 4096) * 4096 + row) = pk;
        }
      }
    }
  }
}

// ---------------- row softmax: S (bf16 [4096][4096]) -> P (bf16) ----------------
__global__ __launch_bounds__(256) void softmax_kernel(const unsigned short* __restrict__ Sm,
                                                      unsigned short* __restrict__ P) {
  const int row = blockIdx.x;
  const int tid = threadIdx.x;
  const unsigned short* src = Sm + (size_t)row * S_DIM;
  float vals[16];
  float mx = -1e30f;
#pragma unroll
  for (int i = 0; i < 4; ++i) {
    ushort4 h = reinterpret_cast<const ushort4*>(src)[tid + i * 256];
    float a = bf2f(h.x), b = bf2f(h.y), c = bf2f(h.z), d = bf2f(h.w);
    vals[i * 4 + 0] = a; vals[i * 4 + 1] = b;
    vals[i * 4 + 2] = c; vals[i * 4 + 3] = d;
    mx = fmaxf(mx, fmaxf(fmaxf(a, b), fmaxf(c, d)));
  }
#pragma unroll
  for (int off = 32; off >= 1; off >>= 1) mx = fmaxf(mx, __shfl_xor(mx, off, 64));
  __shared__ float red[8];
  const int wave = tid >> 6, lane = tid & 63;
  if (lane == 0) red[wave] = mx;
  __syncthreads();
  mx = fmaxf(fmaxf(red[0], red[1]), fmaxf(red[2], red[3]));
  float sum = 0.f;
#pragma unroll
  for (int i = 0; i < 16; ++i) { vals[i] = __expf(vals[i] - mx); sum += vals[i]; }
#pragma unroll
  for (int off = 32; off >= 1; off >>= 1) sum += __shfl_xor(sum, off, 64);
  if (lane == 0) red[4 + wave] = sum;
  __syncthreads();
  sum = red[4] + red[5] + red[6] + red[7];
  const float inv = 1.0f / sum;
  unsigned short* dst = P + (size_t)row * S_DIM;
#pragma unroll
  for (int i = 0; i < 4; ++i) {
    ushort4 pk;
    pk.x = f2bf(vals[i * 4 + 0] * inv);
    pk.y = f2bf(vals[i * 4 + 1] * inv);
    pk.z = f2bf(vals[i * 4 + 2] * inv);
    pk.w = f2bf(vals[i * 4 + 3] * inv);
    reinterpret_cast<ushort4*>(dst)[tid + i * 256] = pk;
  }
}

extern "C" void kernel_launch(void* const* d_in, const int* in_sizes, int n_in,
                              void* d_out, int out_size, void* d_ws, size_t ws_size,
                              hipStream_t stream) {
  const float* x  = (const float*)d_in[0];
  const float* Wq = (const float*)d_in[1];
  const float* Wk = (const float*)d_in[2];
  const float* Wv = (const float*)d_in[3];
  float* out = (float*)d_out;
  char* ws = (char*)d_ws;

  const size_t MB = 1024 * 1024;
  const size_t NEED = 120 * MB;
  if (ws_size < NEED) return;  // visible absmax failure instead of OOB crash

  // Layout (120 MiB):
  //   [0,16)   xb bf16 [4096][2048]     }-> outp0 f32 [4096][2048] at PV
  //   [16,40)  wcat bf16 [6144][2048]   }   (xb+wcat dead after proj)
  //   [40,72)  qkb bf16 [4096][4096] (Q cols 0-2047, K cols 2048-4095) -> P after QK
  //   [72,88)  vt bf16 [2048][4096]
  //   [88,120) Sb bf16 [4096][4096]     -> outp1 f32 at PV (over dead Sb)
  unsigned short* xb   = (unsigned short*)(ws);
  unsigned short* wcat = (unsigned short*)(ws + 16 * MB);
  unsigned short* qkb  = (unsigned short*)(ws + 40 * MB);
  unsigned short* vt   = (unsigned short*)(ws + 72 * MB);
  unsigned short* Sb   = (unsigned short*)(ws + 88 * MB);
  float* outp0 = (float*)(ws);
  float* outp1 = (float*)(ws + 88 * MB);
  unsigned short* P = qkb;

  // allow 128 KiB dynamic LDS (host-side attribute; graph-capture-safe)
  hipFuncSetAttribute(reinterpret_cast<const void*>(&gemm8<EPI_QKV>),
                      hipFuncAttributeMaxDynamicSharedMemorySize, 131072);
  hipFuncSetAttribute(reinterpret_cast<const void*>(&gemm8<EPI_BF16>),
                      hipFuncAttributeMaxDynamicSharedMemorySize, 131072);
  hipFuncSetAttribute(reinterpret_cast<const void*>(&gemm8<EPI_F32>),
                      hipFuncAttributeMaxDynamicSharedMemorySize, 131072);

  const int nx4 = S_DIM * E_DIM / 4;
  const int nw4 = E_DIM * E_DIM / 4;

  // 1) casts: x -> xb; Wq/Wk/Wv -> wcat rows 0/2048/4096 (one dispatch)
  cast_kernel<<<nx4 / 256, 256, 0, stream>>>(x, xb, nx4);
  cast3_kernel<<<3 * nw4 / 256, 256, 0, stream>>>(Wq, Wk, Wv, wcat, nw4);

  // 2) fused QKV projection: [4096][6144] = xb @ wcat^T; V-range written transposed
  gemm8<EPI_QKV><<<dim3(24, 16, 1), 512, 131072, stream>>>(
      xb, wcat, E_DIM, E_DIM, E_DIM, nullptr, qkb, vt, 4096, 1.0f, 0, 0);

  // 3) S = (Q @ K^T) * 1/sqrt(E) -> bf16
  const float scale = 0.022097086912079608f;
  gemm8<EPI_BF16><<<dim3(16, 16, 1), 512, 131072, stream>>>(
      qkb, qkb + 2048, 4096, 4096, E_DIM, nullptr, Sb, nullptr, 4096, scale, 0, 0);

  // 4) softmax -> P (aliases dead qkb)
  softmax_kernel<<<S_DIM, 256, 0, stream>>>(Sb, P);

  // 5) PV split-K=2: out_z = P[:, z*2048:+2048] @ vt[:, z*2048:+2048]^T
  gemm8<EPI_F32><<<dim3(8, 16, 2), 512, 131072, stream>>>(
      P, vt, 4096, 4096, 2048, outp0, nullptr, nullptr, E_DIM, 1.0f,
      2048, (long long)(88 * MB) / 4);

  // 6) out = outp0 + outp1
  add_kernel<<<nx4 / 256, 256, 0, stream>>>(outp0, outp1, out, nx4);
}

// Round 10
// 390.269 us; speedup vs baseline: 1.8573x; 1.0201x over previous
//
#include <hip/hip_runtime.h>
#include <hip/hip_bf16.h>

#define S_DIM 4096
#define E_DIM 2048

typedef __attribute__((ext_vector_type(4))) float f32x4;
typedef __attribute__((ext_vector_type(8))) short bf16x8;

__device__ __forceinline__ unsigned short f2bf(float f) {
  unsigned u = __builtin_bit_cast(unsigned, f);
  u += 0x7FFFu + ((u >> 16) & 1u);   // RNE
  return (unsigned short)(u >> 16);
}
__device__ __forceinline__ float bf2f(unsigned short h) {
  return __builtin_bit_cast(float, ((unsigned)h) << 16);
}

// ---------------- cast f32 -> bf16 ----------------
__global__ __launch_bounds__(256) void cast_kernel(const float* __restrict__ in,
                                                   unsigned short* __restrict__ out,
                                                   int n4) {
  int i = blockIdx.x * 256 + threadIdx.x;
  if (i >= n4) return;
  float4 v = reinterpret_cast<const float4*>(in)[i];
  ushort4 o;
  o.x = f2bf(v.x); o.y = f2bf(v.y); o.z = f2bf(v.z); o.w = f2bf(v.w);
  reinterpret_cast<ushort4*>(out)[i] = o;
}

// cast 3 weight matrices into concatenated wcat in one dispatch
__global__ __launch_bounds__(256) void cast3_kernel(const float* __restrict__ w0,
                                                    const float* __restrict__ w1,
                                                    const float* __restrict__ w2,
                                                    unsigned short* __restrict__ out,
                                                    int n4each) {
  int i = blockIdx.x * 256 + threadIdx.x;
  if (i >= 3 * n4each) return;
  const float* src = (i < n4each) ? w0 : (i < 2 * n4each ? w1 : w2);
  int j = (i < n4each) ? i : (i < 2 * n4each ? i - n4each : i - 2 * n4each);
  float4 v = reinterpret_cast<const float4*>(src)[j];
  ushort4 o;
  o.x = f2bf(v.x); o.y = f2bf(v.y); o.z = f2bf(v.z); o.w = f2bf(v.w);
  reinterpret_cast<ushort4*>(out)[i] = o;
}

// ---------------- common staging: 128-row x 64-col bf16 half-tile ----------------
// 16 subtiles of [16 rows][32 bf16] (1024 B), st_16x32 swizzle
// (byte ^= ((byte>>9)&1)<<5). Linear gload_lds dest + inverse-swizzled source.
__device__ __forceinline__ void stage_half(const unsigned short* __restrict__ g,
                                           int grow0, int ld, int kByte0,
                                           char* ldsHalfBase, int tid) {
#pragma unroll
  for (int p = 0; p < 2; ++p) {
    const int o = (p * 512 + tid) * 16;            // linear LDS byte offset
    const int S = o >> 10;                         // subtile 0..15
    const int oi = o & 1023;
    const int osi = oi ^ (((oi >> 9) & 1) << 5);   // inverse swizzle on source
    const int r  = (S >> 1) * 16 + (osi >> 6);     // row in half-tile 0..127
    const int cb = (S & 1) * 64 + (osi & 63);      // byte col 0..127
    const char* ga = reinterpret_cast<const char*>(g) +
                     ((size_t)(grow0 + r) * ld) * 2 + kByte0 + cb;
    char* la = ldsHalfBase + (o & ~1023);          // wave-uniform base; HW adds lane*16
    __builtin_amdgcn_global_load_lds(
        (const __attribute__((address_space(1))) void*)ga,
        (__attribute__((address_space(3))) void*)la, 16, 0, 0);
  }
}

// ======================= 2-phase 256x256 NT GEMM (bf16 out) ====================
// C = A @ B^T.  BM=BN=256, BK=64, 512 threads = 8 waves (2M x 4N).
// PA(t): read a0,b0,b1 (16); stage A1(t+1)->bufn; bar; lgkm0; 32 MFMA (m0 row)
// PB(t): read a1 (8); stage B0,B1,A0(t+2)->bufc; vmcnt(6); bar; lgkm0; 32 MFMA
// grid: blockIdx.x = M (XCD gets 2 L2-resident A-panels), blockIdx.y = N.

#define MFMA_HALF(AM, AF)                                                      \
  _Pragma("unroll") for (int ks = 0; ks < 2; ++ks)                             \
  _Pragma("unroll") for (int mm = 0; mm < 4; ++mm) {                           \
    acc[(AM) + mm][0] = __builtin_amdgcn_mfma_f32_16x16x32_bf16(               \
        AF[mm][ks], b0[0][ks], acc[(AM) + mm][0], 0, 0, 0);                    \
    acc[(AM) + mm][1] = __builtin_amdgcn_mfma_f32_16x16x32_bf16(               \
        AF[mm][ks], b0[1][ks], acc[(AM) + mm][1], 0, 0, 0);                    \
    acc[(AM) + mm][2] = __builtin_amdgcn_mfma_f32_16x16x32_bf16(               \
        AF[mm][ks], b1[0][ks], acc[(AM) + mm][2], 0, 0, 0);                    \
    acc[(AM) + mm][3] = __builtin_amdgcn_mfma_f32_16x16x32_bf16(               \
        AF[mm][ks], b1[1][ks], acc[(AM) + mm][3], 0, 0, 0);                    \
  }

#define READ_A0(dst, buf)                                                      \
  _Pragma("unroll") for (int mm = 0; mm < 4; ++mm)                             \
  _Pragma("unroll") for (int ks = 0; ks < 2; ++ks)                             \
    dst[mm][ks] = *reinterpret_cast<const bf16x8*>(                            \
        (buf) + aBase + (mm * 2 + ks) * 1024 + rsw);

#define READ_A1(dst, buf)                                                      \
  _Pragma("unroll") for (int mm = 0; mm < 4; ++mm)                             \
  _Pragma("unroll") for (int ks = 0; ks < 2; ++ks)                             \
    dst[mm][ks] = *reinterpret_cast<const bf16x8*>(                            \
        (buf) + aBase + ((4 + mm) * 2 + ks) * 1024 + rsw);

#define READ_B(dst, buf, nh)                                                   \
  _Pragma("unroll") for (int nn = 0; nn < 2; ++nn)                             \
  _Pragma("unroll") for (int ks = 0; ks < 2; ++ks)                             \
    dst[nn][ks] = *reinterpret_cast<const bf16x8*>(                            \
        (buf) + bSub[nh][nn] + ks * 1024 + rsw);

enum { EPI_QKV = 0, EPI_BF16 = 1 };

template <int EPI>
__global__ __launch_bounds__(512, 2) void gemm8(
    const unsigned short* __restrict__ A, const unsigned short* __restrict__ B,
    int lda, int ldb, int K,
    unsigned short* __restrict__ Cb, unsigned short* __restrict__ Ct,
    int ldc, float scale) {
  extern __shared__ char lds[];

  const int tid = threadIdx.x;
  const int rowA0 = blockIdx.x * 256;   // bx = M: XCD holds 2 A-panels in L2
  const int rowB0 = blockIdx.y * 256;

  const int wave = tid >> 6;
  const int lane = tid & 63;
  const int wm = wave >> 2;   // 0..1 (M)
  const int wn = wave & 3;    // 0..3 (N)
  const int l15 = lane & 15;
  const int kg = lane >> 4;
  const int rsw = (l15 * 64 + kg * 16) ^ ((l15 & 8) << 2);  // swizzled in-subtile off

  int bSub[2][2];
#pragma unroll
  for (int nh = 0; nh < 2; ++nh)
#pragma unroll
    for (int nn = 0; nn < 2; ++nn) {
      const int row = wn * 64 + nh * 32 + nn * 16;
      bSub[nh][nn] = 32768 + (row >> 7) * 16384 + ((row & 127) >> 4) * 2048;
    }
  const int aBase = wm * 16384;

  f32x4 acc[8][4];
#pragma unroll
  for (int mi = 0; mi < 8; ++mi)
#pragma unroll
    for (int ni = 0; ni < 4; ++ni) acc[mi][ni] = (f32x4){0.f, 0.f, 0.f, 0.f};

  const int NT = K / 64;
  char* buf0 = lds;
  char* buf1 = lds + 65536;

  // ---- prologue: tile0 fully (8), tile1 B+A0 (6); vmcnt(6) retires tile0.
  stage_half(B, rowB0,       ldb, 0,   buf0 + 32768, tid);
  stage_half(B, rowB0 + 128, ldb, 0,   buf0 + 49152, tid);
  stage_half(A, rowA0,       lda, 0,   buf0 + 0,     tid);
  stage_half(A, rowA0 + 128, lda, 0,   buf0 + 16384, tid);
  stage_half(B, rowB0,       ldb, 128, buf1 + 32768, tid);
  stage_half(B, rowB0 + 128, ldb, 128, buf1 + 49152, tid);
  stage_half(A, rowA0,       lda, 128, buf1 + 0,     tid);
  asm volatile("s_waitcnt vmcnt(6)" ::: "memory");
  __builtin_amdgcn_sched_barrier(0);
  __builtin_amdgcn_s_barrier();   // tile0 resident for all waves

  for (int t = 0; t < NT; ++t) {
    char* bufc = lds + (t & 1) * 65536;
    char* bufn = lds + ((t & 1) ^ 1) * 65536;
    bf16x8 a0[4][2], a1[4][2], b0[2][2], b1[2][2];

    // ---------- PA
    READ_A0(a0, bufc)
    READ_B(b0, bufc, 0)
    READ_B(b1, bufc, 1)
    if (t + 1 < NT)
      stage_half(A, rowA0 + 128, lda, (t + 1) * 128, bufn + 16384, tid);
    __builtin_amdgcn_sched_barrier(0);
    __builtin_amdgcn_s_barrier();
    asm volatile("s_waitcnt lgkmcnt(0)" ::: "memory");
    __builtin_amdgcn_sched_barrier(0);
    __builtin_amdgcn_s_setprio(1);
    MFMA_HALF(0, a0)
    __builtin_amdgcn_s_setprio(0);
    __builtin_amdgcn_s_barrier();

    // ---------- PB
    READ_A1(a1, bufc)
    if (t + 2 < NT) {
      const int kb = (t + 2) * 128;
      stage_half(B, rowB0,       ldb, kb, bufc + 32768, tid);
      stage_half(B, rowB0 + 128, ldb, kb, bufc + 49152, tid);
      stage_half(A, rowA0,       lda, kb, bufc + 0,     tid);
      asm volatile("s_waitcnt vmcnt(6)" ::: "memory");
    } else {
      asm volatile("s_waitcnt vmcnt(0)" ::: "memory");
    }
    __builtin_amdgcn_sched_barrier(0);
    __builtin_amdgcn_s_barrier();
    asm volatile("s_waitcnt lgkmcnt(0)" ::: "memory");
    __builtin_amdgcn_sched_barrier(0);
    __builtin_amdgcn_s_setprio(1);
    MFMA_HALF(4, a1)
    __builtin_amdgcn_s_setprio(0);
    __builtin_amdgcn_s_barrier();
  }

  // ---------- epilogue: C/D frag mapping col=lane&15, row=(lane>>4)*4+reg
  const int r0 = rowA0 + wm * 128;
  const int c0 = rowB0 + wn * 64;
#pragma unroll
  for (int mi = 0; mi < 8; ++mi) {
    const int row = r0 + (mi >> 2) * 64 + (mi & 3) * 16 + kg * 4;
#pragma unroll
    for (int ni = 0; ni < 4; ++ni) {
      const int col = c0 + (ni >> 1) * 32 + (ni & 1) * 16 + l15;
      f32x4 v = acc[mi][ni];
      if constexpr (EPI == EPI_BF16) {
#pragma unroll
        for (int r = 0; r < 4; ++r)
          Cb[(size_t)(row + r) * ldc + col] = f2bf(v[r] * scale);
      } else {  // EPI_QKV: cols<4096 -> qkb [4096][4096]; cols>=4096 -> vt transposed
        if (rowB0 < 4096) {
#pragma unroll
          for (int r = 0; r < 4; ++r)
            Cb[(size_t)(row + r) * 4096 + col] = f2bf(v[r]);
        } else {
          ushort4 pk;
          pk.x = f2bf(v[0]); pk.y = f2bf(v[1]);
          pk.z = f2bf(v[2]); pk.w = f2bf(v[3]);
          *reinterpret_cast<ushort4*>(Ct + (size_t)(col - 4096) * 4096 + row) = pk;
        }
      }
    }
  }
}

// ======================= PV: 256x128 NT GEMM, f32 out, no split-K ==============
// out = P @ vt^T.  BM=256, BN=128, BK=64, K=4096. 512 threads = 8 waves (2M x 4N);
// per-wave 128x32 = acc[8][2]. LDS 96K: 2 bufs x (A 32K + B 16K).
// PA(t): read a(mi0..3)+b (12); stage A1(t+1)->bufn; bar; lgkm0; 16 MFMA
// PB(t): read a(mi4..7) (8); stage B,A0(t+2)->bufc; vmcnt(4); bar; lgkm0; 16 MFMA
__global__ __launch_bounds__(512, 2) void pv128(
    const unsigned short* __restrict__ A, const unsigned short* __restrict__ B,
    float* __restrict__ Cf) {
  extern __shared__ char lds[];
  const int tid = threadIdx.x;
  const int rowA0 = blockIdx.x * 256;   // M
  const int colB0 = blockIdx.y * 128;   // N
  const int wave = tid >> 6, lane = tid & 63;
  const int wm = wave >> 2, wn = wave & 3;
  const int l15 = lane & 15, kg = lane >> 4;
  const int rsw = (l15 * 64 + kg * 16) ^ ((l15 & 8) << 2);
  const int aBase = wm * 16384;                 // A half for this wave
  const int bBase = 32768 + wn * 2 * 2048;      // B subtiles wn*2, wn*2+1

  f32x4 acc[8][2];
#pragma unroll
  for (int mi = 0; mi < 8; ++mi) {
    acc[mi][0] = (f32x4){0.f, 0.f, 0.f, 0.f};
    acc[mi][1] = (f32x4){0.f, 0.f, 0.f, 0.f};
  }

  const int NT = S_DIM / 64;  // 64
  char* buf0 = lds;
  char* buf1 = lds + 49152;

  // prologue: tile0 {B,A0,A1}, tile1 {B,A0}; retire tile0
  stage_half(B, colB0,       S_DIM, 0,   buf0 + 32768, tid);
  stage_half(A, rowA0,       S_DIM, 0,   buf0 + 0,     tid);
  stage_half(A, rowA0 + 128, S_DIM, 0,   buf0 + 16384, tid);
  stage_half(B, colB0,       S_DIM, 128, buf1 + 32768, tid);
  stage_half(A, rowA0,       S_DIM, 128, buf1 + 0,     tid);
  asm volatile("s_waitcnt vmcnt(4)" ::: "memory");
  __builtin_amdgcn_sched_barrier(0);
  __builtin_amdgcn_s_barrier();

  for (int t = 0; t < NT; ++t) {
    char* bufc = lds + (t & 1) * 49152;
    char* bufn = lds + ((t & 1) ^ 1) * 49152;
    bf16x8 a0[4][2], a1[4][2], bf[2][2];

    // PA: read a(mi0..3) + b; stage A1(t+1)
#pragma unroll
    for (int mm = 0; mm < 4; ++mm)
#pragma unroll
      for (int ks = 0; ks < 2; ++ks)
        a0[mm][ks] = *reinterpret_cast<const bf16x8*>(
            bufc + aBase + mm * 2048 + ks * 1024 + rsw);
#pragma unroll
    for (int nn = 0; nn < 2; ++nn)
#pragma unroll
      for (int ks = 0; ks < 2; ++ks)
        bf[nn][ks] = *reinterpret_cast<const bf16x8*>(
            bufc + bBase + nn * 2048 + ks * 1024 + rsw);
    if (t + 1 < NT)
      stage_half(A, rowA0 + 128, S_DIM, (t + 1) * 128, bufn + 16384, tid);
    __builtin_amdgcn_sched_barrier(0);
    __builtin_amdgcn_s_barrier();
    asm volatile("s_waitcnt lgkmcnt(0)" ::: "memory");
    __builtin_amdgcn_sched_barrier(0);
    __builtin_amdgcn_s_setprio(1);
#pragma unroll
    for (int ks = 0; ks < 2; ++ks)
#pragma unroll
      for (int mm = 0; mm < 4; ++mm) {
        acc[mm][0] = __builtin_amdgcn_mfma_f32_16x16x32_bf16(
            a0[mm][ks], bf[0][ks], acc[mm][0], 0, 0, 0);
        acc[mm][1] = __builtin_amdgcn_mfma_f32_16x16x32_bf16(
            a0[mm][ks], bf[1][ks], acc[mm][1], 0, 0, 0);
      }
    __builtin_amdgcn_s_setprio(0);
    __builtin_amdgcn_s_barrier();

    // PB: read a(mi4..7); stage B,A0(t+2); vmcnt(4)
#pragma unroll
    for (int mm = 0; mm < 4; ++mm)
#pragma unroll
      for (int ks = 0; ks < 2; ++ks)
        a1[mm][ks] = *reinterpret_cast<const bf16x8*>(
            bufc + aBase + (4 + mm) * 2048 + ks * 1024 + rsw);
    if (t + 2 < NT) {
      const int kb = (t + 2) * 128;
      stage_half(B, colB0, S_DIM, kb, bufc + 32768, tid);
      stage_half(A, rowA0, S_DIM, kb, bufc + 0,     tid);
      asm volatile("s_waitcnt vmcnt(4)" ::: "memory");
    } else {
      asm volatile("s_waitcnt vmcnt(0)" ::: "memory");
    }
    __builtin_amdgcn_sched_barrier(0);
    __builtin_amdgcn_s_barrier();
    asm volatile("s_waitcnt lgkmcnt(0)" ::: "memory");
    __builtin_amdgcn_sched_barrier(0);
    __builtin_amdgcn_s_setprio(1);
#pragma unroll
    for (int ks = 0; ks < 2; ++ks)
#pragma unroll
      for (int mm = 0; mm < 4; ++mm) {
        acc[4 + mm][0] = __builtin_amdgcn_mfma_f32_16x16x32_bf16(
            a1[mm][ks], bf[0][ks], acc[4 + mm][0], 0, 0, 0);
        acc[4 + mm][1] = __builtin_amdgcn_mfma_f32_16x16x32_bf16(
            a1[mm][ks], bf[1][ks], acc[4 + mm][1], 0, 0, 0);
      }
    __builtin_amdgcn_s_setprio(0);
    __builtin_amdgcn_s_barrier();
  }

  // epilogue: f32 direct to out [4096][2048]
#pragma unroll
  for (int mi = 0; mi < 8; ++mi) {
    const int row = rowA0 + wm * 128 + mi * 16 + kg * 4;
#pragma unroll
    for (int ni = 0; ni < 2; ++ni) {
      const int col = colB0 + wn * 32 + ni * 16 + l15;
      f32x4 v = acc[mi][ni];
#pragma unroll
      for (int r = 0; r < 4; ++r)
        Cf[(size_t)(row + r) * E_DIM + col] = v[r];
    }
  }
}

// ---------------- row softmax: S (bf16 [4096][4096]) -> P (bf16) ----------------
__global__ __launch_bounds__(256) void softmax_kernel(const unsigned short* __restrict__ Sm,
                                                      unsigned short* __restrict__ P) {
  const int row = blockIdx.x;
  const int tid = threadIdx.x;
  const unsigned short* src = Sm + (size_t)row * S_DIM;
  float vals[16];
  float mx = -1e30f;
#pragma unroll
  for (int i = 0; i < 4; ++i) {
    ushort4 h = reinterpret_cast<const ushort4*>(src)[tid + i * 256];
    float a = bf2f(h.x), b = bf2f(h.y), c = bf2f(h.z), d = bf2f(h.w);
    vals[i * 4 + 0] = a; vals[i * 4 + 1] = b;
    vals[i * 4 + 2] = c; vals[i * 4 + 3] = d;
    mx = fmaxf(mx, fmaxf(fmaxf(a, b), fmaxf(c, d)));
  }
#pragma unroll
  for (int off = 32; off >= 1; off >>= 1) mx = fmaxf(mx, __shfl_xor(mx, off, 64));
  __shared__ float red[8];
  const int wave = tid >> 6, lane = tid & 63;
  if (lane == 0) red[wave] = mx;
  __syncthreads();
  mx = fmaxf(fmaxf(red[0], red[1]), fmaxf(red[2], red[3]));
  float sum = 0.f;
#pragma unroll
  for (int i = 0; i < 16; ++i) { vals[i] = __expf(vals[i] - mx); sum += vals[i]; }
#pragma unroll
  for (int off = 32; off >= 1; off >>= 1) sum += __shfl_xor(sum, off, 64);
  if (lane == 0) red[4 + wave] = sum;
  __syncthreads();
  sum = red[4] + red[5] + red[6] + red[7];
  const float inv = 1.0f / sum;
  unsigned short* dst = P + (size_t)row * S_DIM;
#pragma unroll
  for (int i = 0; i < 4; ++i) {
    ushort4 pk;
    pk.x = f2bf(vals[i * 4 + 0] * inv);
    pk.y = f2bf(vals[i * 4 + 1] * inv);
    pk.z = f2bf(vals[i * 4 + 2] * inv);
    pk.w = f2bf(vals[i * 4 + 3] * inv);
    reinterpret_cast<ushort4*>(dst)[tid + i * 256] = pk;
  }
}

extern "C" void kernel_launch(void* const* d_in, const int* in_sizes, int n_in,
                              void* d_out, int out_size, void* d_ws, size_t ws_size,
                              hipStream_t stream) {
  const float* x  = (const float*)d_in[0];
  const float* Wq = (const float*)d_in[1];
  const float* Wk = (const float*)d_in[2];
  const float* Wv = (const float*)d_in[3];
  float* out = (float*)d_out;
  char* ws = (char*)d_ws;

  const size_t MB = 1024 * 1024;
  const size_t NEED = 120 * MB;
  if (ws_size < NEED) return;  // visible absmax failure instead of OOB crash

  // Layout (120 MiB):
  //   [0,16)   xb bf16 [4096][2048]
  //   [16,40)  wcat bf16 [6144][2048]
  //   [40,72)  qkb bf16 [4096][4096] (Q cols 0-2047, K cols 2048-4095) -> P after QK
  //   [72,88)  vt bf16 [2048][4096]
  //   [88,120) Sb bf16 [4096][4096]
  unsigned short* xb   = (unsigned short*)(ws);
  unsigned short* wcat = (unsigned short*)(ws + 16 * MB);
  unsigned short* qkb  = (unsigned short*)(ws + 40 * MB);
  unsigned short* vt   = (unsigned short*)(ws + 72 * MB);
  unsigned short* Sb   = (unsigned short*)(ws + 88 * MB);
  unsigned short* P = qkb;

  // dynamic LDS attributes (host-side, graph-capture-safe)
  hipFuncSetAttribute(reinterpret_cast<const void*>(&gemm8<EPI_QKV>),
                      hipFuncAttributeMaxDynamicSharedMemorySize, 131072);
  hipFuncSetAttribute(reinterpret_cast<const void*>(&gemm8<EPI_BF16>),
                      hipFuncAttributeMaxDynamicSharedMemorySize, 131072);
  hipFuncSetAttribute(reinterpret_cast<const void*>(&pv128),
                      hipFuncAttributeMaxDynamicSharedMemorySize, 98304);

  const int nx4 = S_DIM * E_DIM / 4;
  const int nw4 = E_DIM * E_DIM / 4;

  // 1) casts
  cast_kernel<<<nx4 / 256, 256, 0, stream>>>(x, xb, nx4);
  cast3_kernel<<<3 * nw4 / 256, 256, 0, stream>>>(Wq, Wk, Wv, wcat, nw4);

  // 2) fused QKV projection: [4096][6144] = xb @ wcat^T; V-range written transposed
  gemm8<EPI_QKV><<<dim3(16, 24), 512, 131072, stream>>>(
      xb, wcat, E_DIM, E_DIM, E_DIM, qkb, vt, 4096, 1.0f);

  // 3) S = (Q @ K^T) * 1/sqrt(E) -> bf16
  const float scale = 0.022097086912079608f;
  gemm8<EPI_BF16><<<dim3(16, 16), 512, 131072, stream>>>(
      qkb, qkb + 2048, 4096, 4096, E_DIM, Sb, nullptr, 4096, scale);

  // 4) softmax -> P (aliases dead qkb)
  softmax_kernel<<<S_DIM, 256, 0, stream>>>(Sb, P);

  // 5) out = P @ vt^T  (f32, direct, no split-K)
  pv128<<<dim3(16, 16), 512, 98304, stream>>>(P, vt, out);
}